// Round 6
// baseline (1151.801 us; speedup 1.0000x reference)
//
#include <hip/hip_runtime.h>
#include <cstddef>
#include <cstdint>

// Problem constants
constexpr int cB = 8, cH = 8, cN = 4096, cD = 64, cM = 64, cL = 64;

// ---------------------------------------------------------------------------
// K1: landmarks  q_l/k_l[bh][m][d] = mean over l=64 tokens
// ---------------------------------------------------------------------------
__global__ void k_landmarks(const float* __restrict__ q, const float* __restrict__ k,
                            float* __restrict__ ql, float* __restrict__ kl) {
  int bm = blockIdx.x;          // BH*M = 4096
  int bh = bm >> 6, m = bm & 63;
  int d = threadIdx.x;          // 64
  size_t base = ((size_t)bh * cN + (size_t)m * cL) * cD + d;
  float sq = 0.f, sk = 0.f;
  for (int t = 0; t < cL; ++t) {
    sq += q[base + (size_t)t * cD];
    sk += k[base + (size_t)t * cD];
  }
  size_t ob = ((size_t)bh * cM + m) * cD + d;
  ql[ob] = sq * (1.0f / cL);
  kl[ob] = sk * (1.0f / cL);
}

// ---------------------------------------------------------------------------
// K2: sim2 = q_l k_l^T, mix heads (Wsim2), softmax rows, write attn2.
// Also atomicMax of global col-sum max (scal[0]) and row-sum max (scal[1]).
// ---------------------------------------------------------------------------
__global__ void __launch_bounds__(256) k_sim2(const float* __restrict__ ql,
                                              const float* __restrict__ kl,
                                              const float* __restrict__ Wsim2,
                                              float* __restrict__ attn2,
                                              unsigned int* __restrict__ scal) {
  __shared__ float qs[64][65];
  __shared__ float ks[64][65];
  __shared__ float acc[64 * 65];
  int b = blockIdx.x >> 3, kk = blockIdx.x & 7;
  int tid = threadIdx.x;
  for (int idx = tid; idx < 64 * 64; idx += 256)
    acc[(idx >> 6) * 65 + (idx & 63)] = 0.f;
  int ri = (tid >> 4) * 4, ci = (tid & 15) * 4;
  for (int h = 0; h < 8; ++h) {
    __syncthreads();
    const float* qg = ql + (size_t)(b * 8 + h) * 4096;
    const float* kg = kl + (size_t)(b * 8 + h) * 4096;
    for (int idx = tid; idx < 4096; idx += 256) {
      qs[idx >> 6][idx & 63] = qg[idx];
      ks[idx >> 6][idx & 63] = kg[idx];
    }
    __syncthreads();
    float w = Wsim2[h * 8 + kk];
    float s[4][4] = {};
    for (int d = 0; d < 64; ++d) {
      float a0 = qs[ri][d], a1 = qs[ri + 1][d], a2 = qs[ri + 2][d], a3 = qs[ri + 3][d];
      float b0 = ks[ci][d], b1 = ks[ci + 1][d], b2 = ks[ci + 2][d], b3 = ks[ci + 3][d];
      s[0][0] += a0 * b0; s[0][1] += a0 * b1; s[0][2] += a0 * b2; s[0][3] += a0 * b3;
      s[1][0] += a1 * b0; s[1][1] += a1 * b1; s[1][2] += a1 * b2; s[1][3] += a1 * b3;
      s[2][0] += a2 * b0; s[2][1] += a2 * b1; s[2][2] += a2 * b2; s[2][3] += a2 * b3;
      s[3][0] += a3 * b0; s[3][1] += a3 * b1; s[3][2] += a3 * b2; s[3][3] += a3 * b3;
    }
    #pragma unroll
    for (int x = 0; x < 4; ++x)
      #pragma unroll
      for (int y = 0; y < 4; ++y)
        acc[(ri + x) * 65 + ci + y] += w * s[x][y];
  }
  __syncthreads();
  if (tid < 64) {
    float mx = -1e30f;
    for (int j = 0; j < 64; ++j) mx = fmaxf(mx, acc[tid * 65 + j]);
    float s = 0.f;
    for (int j = 0; j < 64; ++j) {
      float e = expf(acc[tid * 65 + j] - mx);
      acc[tid * 65 + j] = e;
      s += e;
    }
    float inv = 1.0f / s;
    float rs = 0.f;
    for (int j = 0; j < 64; ++j) {
      float p = acc[tid * 65 + j] * inv;
      acc[tid * 65 + j] = p;
      rs += p;
    }
    atomicMax(scal + 1, __float_as_uint(rs));
  }
  __syncthreads();
  if (tid < 64) {
    float cs = 0.f;
    for (int i = 0; i < 64; ++i) cs += acc[i * 65 + tid];
    atomicMax(scal + 0, __float_as_uint(cs));
  }
  __syncthreads();
  float* op = attn2 + (size_t)(b * 8 + kk) * 4096;
  for (int idx = tid; idx < 4096; idx += 256)
    op[idx] = acc[(idx >> 6) * 65 + (idx & 63)];
}

// ---------------------------------------------------------------------------
// K2b: in-place transpose of kl [bh][m][d] -> [bh][d][m].
// ---------------------------------------------------------------------------
__global__ void k_klT(float* __restrict__ kl) {
  __shared__ float t[64 * 65];
  int bh = blockIdx.x, tid = threadIdx.x;
  float* p = kl + (size_t)bh * 4096;
  for (int idx = tid; idx < 4096; idx += 256)
    t[(idx >> 6) * 65 + (idx & 63)] = p[idx];
  __syncthreads();
  for (int idx = tid; idx < 4096; idx += 256)
    p[idx] = t[(idx & 63) * 65 + (idx >> 6)];
}

// ---------------------------------------------------------------------------
// K3: Moore-Penrose pinv, 6 Newton-Schulz iterations in LDS, per (b,k) block.
// ---------------------------------------------------------------------------
__device__ __forceinline__ void mm64(float* __restrict__ Dst, const float* S,
                                     float c0, float c1, const float* __restrict__ P,
                                     const float* __restrict__ Q, int tid) {
  int ri = (tid >> 4) * 4, ci = (tid & 15) * 4;
  float s[4][4] = {};
  for (int k = 0; k < 64; ++k) {
    float a0 = P[(ri + 0) * 65 + k], a1 = P[(ri + 1) * 65 + k];
    float a2 = P[(ri + 2) * 65 + k], a3 = P[(ri + 3) * 65 + k];
    float b0 = Q[k * 65 + ci + 0], b1 = Q[k * 65 + ci + 1];
    float b2 = Q[k * 65 + ci + 2], b3 = Q[k * 65 + ci + 3];
    s[0][0] += a0 * b0; s[0][1] += a0 * b1; s[0][2] += a0 * b2; s[0][3] += a0 * b3;
    s[1][0] += a1 * b0; s[1][1] += a1 * b1; s[1][2] += a1 * b2; s[1][3] += a1 * b3;
    s[2][0] += a2 * b0; s[2][1] += a2 * b1; s[2][2] += a2 * b2; s[2][3] += a2 * b3;
    s[3][0] += a3 * b0; s[3][1] += a3 * b1; s[3][2] += a3 * b2; s[3][3] += a3 * b3;
  }
  #pragma unroll
  for (int x = 0; x < 4; ++x)
    #pragma unroll
    for (int y = 0; y < 4; ++y) {
      float r = c1 * s[x][y];
      if (S) r += c0 * S[(ri + x) * 65 + ci + y];
      Dst[(ri + x) * 65 + ci + y] = r;
    }
}

__global__ void __launch_bounds__(256) k_pinv(const float* __restrict__ attn2,
                                              float* __restrict__ attn2inv,
                                              const unsigned int* __restrict__ scal) {
  __shared__ float bufs[5][64 * 65];
  float* X = bufs[0];
  float* Z = bufs[1];
  float* T1 = bufs[2];
  float* T2 = bufs[3];
  float* T3 = bufs[4];
  int tid = threadIdx.x;
  const float* xg = attn2 + (size_t)blockIdx.x * 4096;
  for (int idx = tid; idx < 4096; idx += 256)
    X[(idx >> 6) * 65 + (idx & 63)] = xg[idx];
  float denom = __uint_as_float(scal[0]) * __uint_as_float(scal[1]);
  float invd = 1.0f / denom;
  __syncthreads();
  for (int idx = tid; idx < 4096; idx += 256) {
    int i = idx >> 6, j = idx & 63;
    Z[i * 65 + j] = X[j * 65 + i] * invd;
  }
  __syncthreads();
  for (int it = 0; it < 6; ++it) {
    mm64(T1, nullptr, 0.f, 1.f, X, Z, tid);          __syncthreads();
    mm64(T2, T1, 7.f, -1.f, T1, T1, tid);            __syncthreads();
    mm64(T3, T1, 15.f, -1.f, T1, T2, tid);           __syncthreads();
    mm64(T2, Z, 13.f * 0.25f, -0.25f, Z, T3, tid);   __syncthreads();
    float* tmp = Z; Z = T2; T2 = tmp;
  }
  float* og = attn2inv + (size_t)blockIdx.x * 4096;
  for (int idx = tid; idx < 4096; idx += 256)
    og[idx] = Z[(idx >> 6) * 65 + (idx & 63)];
}

// ---------------------------------------------------------------------------
// K4: head-mix of 64x64 mats: out[b][k2] = sum_k in[b][k] * W[k][k2]
// ---------------------------------------------------------------------------
__global__ void k_mix_heads64(const float* __restrict__ in, const float* __restrict__ W,
                              float* __restrict__ out) {
  int b = blockIdx.x >> 3, k2 = blockIdx.x & 7;
  int tid = threadIdx.x;
  __shared__ float w[8];
  if (tid < 8) w[tid] = W[tid * 8 + k2];
  __syncthreads();
  const float* ib = in + (size_t)b * 8 * 4096;
  float* ob = out + ((size_t)b * 8 + k2) * 4096;
  for (int idx = tid; idx < 4096; idx += 256) {
    float s = 0.f;
    #pragma unroll
    for (int k = 0; k < 8; ++k) s += ib[(size_t)k * 4096 + idx] * w[k];
    ob[idx] = s;
  }
}

// ---------------------------------------------------------------------------
// K5: sim3m[b][k][i][j] = sum_h Wsim3[h][k]*(q_l[b,h,i,:].k[b,h,j,:])
// ---------------------------------------------------------------------------
__global__ void __launch_bounds__(512) k_sim3(const float* __restrict__ ql,
                                              const float* __restrict__ kg,
                                              const float* __restrict__ Wsim3,
                                              float* __restrict__ sim3m) {
  __shared__ float qls[64 * 65];   // [i][d] pitch 65
  __shared__ float ksT[64 * 36];   // [d][j] pitch 36 (16B-aligned float4 rows)
  __shared__ float w3[64];
  int b = blockIdx.x >> 7, jt = blockIdx.x & 127;
  int j0 = jt * 32, tid = threadIdx.x;
  if (tid < 64) w3[tid] = Wsim3[tid];
  int i = tid >> 3, jb = (tid & 7) * 4;
  float acc[8][4] = {};
  for (int h = 0; h < 8; ++h) {
    __syncthreads();
    const float* qg = ql + (size_t)(b * 8 + h) * 4096;
    for (int idx = tid; idx < 4096; idx += 512)
      qls[(idx >> 6) * 65 + (idx & 63)] = qg[idx];
    const float* kp = kg + ((size_t)(b * 8 + h) * cN + j0) * 64;
    for (int idx = tid; idx < 2048; idx += 512) {
      int j = idx >> 6, d = idx & 63;
      ksT[d * 36 + j] = kp[idx];
    }
    __syncthreads();
    float s[4] = {};
    for (int d = 0; d < 64; ++d) {
      float a = qls[i * 65 + d];
      float4 kv = *(const float4*)&ksT[d * 36 + jb];
      s[0] += a * kv.x; s[1] += a * kv.y; s[2] += a * kv.z; s[3] += a * kv.w;
    }
    #pragma unroll
    for (int k = 0; k < 8; ++k) {
      float w = w3[h * 8 + k];
      #pragma unroll
      for (int c = 0; c < 4; ++c) acc[k][c] += w * s[c];
    }
  }
  #pragma unroll
  for (int k = 0; k < 8; ++k) {
    float* op = sim3m + ((size_t)((b * 8 + k) * 64 + i)) * cN + j0 + jb;
    *(float4*)op = make_float4(acc[k][0], acc[k][1], acc[k][2], acc[k][3]);
  }
}

// ---------------------------------------------------------------------------
// K6: row stats for softmax over j=4096: one block per (b,k,i) row.
// ---------------------------------------------------------------------------
__global__ void k_stats3(const float* __restrict__ sim3m, float* __restrict__ rmax,
                         float* __restrict__ rsum) {
  int row = blockIdx.x; // 4096
  const float* rp = sim3m + (size_t)row * cN;
  int tid = threadIdx.x;
  float vv[16];
  float mx = -1e30f;
  #pragma unroll
  for (int t = 0; t < 16; ++t) {
    vv[t] = rp[tid + t * 256];
    mx = fmaxf(mx, vv[t]);
  }
  __shared__ float red[8];
  for (int off = 32; off > 0; off >>= 1) mx = fmaxf(mx, __shfl_down(mx, off));
  if ((tid & 63) == 0) red[tid >> 6] = mx;
  __syncthreads();
  mx = fmaxf(fmaxf(red[0], red[1]), fmaxf(red[2], red[3]));
  float s = 0.f;
  #pragma unroll
  for (int t = 0; t < 16; ++t) s += expf(vv[t] - mx);
  for (int off = 32; off > 0; off >>= 1) s += __shfl_down(s, off);
  __syncthreads();
  if ((tid & 63) == 0) red[4 + (tid >> 6)] = s;
  __syncthreads();
  if (tid == 0) {
    rmax[row] = mx;
    rsum[row] = red[4] + red[5] + red[6] + red[7];
  }
}

// ---------------------------------------------------------------------------
// K7: in-place softmax + Wattn3 head-mix on sim3m, register-resident.
// ---------------------------------------------------------------------------
__global__ void __launch_bounds__(256) k_smx3(float* __restrict__ sim3m,
                                              const float* __restrict__ rmax,
                                              const float* __restrict__ rsum,
                                              const float* __restrict__ Wattn3) {
  __shared__ float w[64];
  int tid = threadIdx.x;
  if (tid < 64) w[tid] = Wattn3[tid];
  __syncthreads();
  int gid = blockIdx.x * 256 + tid;   // 2^21 = 8b * 64i * 4096j
  int j = gid & 4095;
  int i = (gid >> 12) & 63;
  int b = gid >> 18;
  float p[8];
  #pragma unroll
  for (int k = 0; k < 8; ++k) {
    int row = (b * 8 + k) * 64 + i;
    p[k] = expf(sim3m[(size_t)row * cN + j] - rmax[row]) / rsum[row];
  }
  #pragma unroll
  for (int k2 = 0; k2 < 8; ++k2) {
    float t = 0.f;
    #pragma unroll
    for (int k = 0; k < 8; ++k) t += p[k] * w[k * 8 + k2];
    int row = (b * 8 + k2) * 64 + i;
    sim3m[(size_t)row * cN + j] = t;
  }
}

// ---------------------------------------------------------------------------
// K8: T3 partials: T3p[c][bh] = attn3f[bh][:, cchunk] @ v[bh][cchunk, :]
// ---------------------------------------------------------------------------
__global__ void __launch_bounds__(256) k_t3(const float* __restrict__ attn3f,
                                            const float* __restrict__ v,
                                            float* __restrict__ T3p) {
  __shared__ float As[64][65];
  __shared__ float Vs[64][68];
  int bh = blockIdx.x >> 2, chunk = blockIdx.x & 3;
  int tid = threadIdx.x;
  int ri = (tid >> 4) * 4, ci = (tid & 15) * 4;
  float acc[4][4] = {};
  for (int jt = chunk * 16; jt < chunk * 16 + 16; ++jt) {
    __syncthreads();
    const float* ap = attn3f + (size_t)bh * 64 * cN + jt * 64;
    for (int idx = tid; idx < 4096; idx += 256)
      As[idx >> 6][idx & 63] = ap[(size_t)(idx >> 6) * cN + (idx & 63)];
    const float* vp = v + ((size_t)bh * cN + jt * 64) * 64;
    for (int idx = tid; idx < 4096; idx += 256)
      Vs[idx >> 6][idx & 63] = vp[idx];
    __syncthreads();
    for (int j = 0; j < 64; ++j) {
      float a0 = As[ri][j], a1 = As[ri + 1][j], a2 = As[ri + 2][j], a3 = As[ri + 3][j];
      float b0 = Vs[j][ci], b1 = Vs[j][ci + 1], b2 = Vs[j][ci + 2], b3 = Vs[j][ci + 3];
      acc[0][0] += a0 * b0; acc[0][1] += a0 * b1; acc[0][2] += a0 * b2; acc[0][3] += a0 * b3;
      acc[1][0] += a1 * b0; acc[1][1] += a1 * b1; acc[1][2] += a1 * b2; acc[1][3] += a1 * b3;
      acc[2][0] += a2 * b0; acc[2][1] += a2 * b1; acc[2][2] += a2 * b2; acc[2][3] += a2 * b3;
      acc[3][0] += a3 * b0; acc[3][1] += a3 * b1; acc[3][2] += a3 * b2; acc[3][3] += a3 * b3;
    }
  }
  float* op = T3p + ((size_t)chunk * 64 + bh) * 4096;
  #pragma unroll
  for (int x = 0; x < 4; ++x)
    #pragma unroll
    for (int y = 0; y < 4; ++y)
      op[(ri + x) * 64 + ci + y] = acc[x][y];
}

// ---------------------------------------------------------------------------
// K9: T2[bh] = attn2m[bh] @ (sum of 4 T3 partials). Block per bh.
// ---------------------------------------------------------------------------
__global__ void __launch_bounds__(256) k_t2(const float* __restrict__ attn2m,
                                            const float* __restrict__ T3p,
                                            float* __restrict__ T2) {
  __shared__ float As[64][65];
  __shared__ float Bs[64][68];
  int bh = blockIdx.x, tid = threadIdx.x;
  const float* ap = attn2m + (size_t)bh * 4096;
  for (int idx = tid; idx < 4096; idx += 256) {
    As[idx >> 6][idx & 63] = ap[idx];
    float s = 0.f;
    #pragma unroll
    for (int c = 0; c < 4; ++c) s += T3p[((size_t)c * 64 + bh) * 4096 + idx];
    Bs[idx >> 6][idx & 63] = s;
  }
  __syncthreads();
  int ri = (tid >> 4) * 4, ci = (tid & 15) * 4;
  float acc[4][4] = {};
  for (int j = 0; j < 64; ++j) {
    float a0 = As[ri][j], a1 = As[ri + 1][j], a2 = As[ri + 2][j], a3 = As[ri + 3][j];
    float b0 = Bs[j][ci], b1 = Bs[j][ci + 1], b2 = Bs[j][ci + 2], b3 = Bs[j][ci + 3];
    acc[0][0] += a0 * b0; acc[0][1] += a0 * b1; acc[0][2] += a0 * b2; acc[0][3] += a0 * b3;
    acc[1][0] += a1 * b0; acc[1][1] += a1 * b1; acc[1][2] += a1 * b2; acc[1][3] += a1 * b3;
    acc[2][0] += a2 * b0; acc[2][1] += a2 * b1; acc[2][2] += a2 * b2; acc[2][3] += a2 * b3;
    acc[3][0] += a3 * b0; acc[3][1] += a3 * b1; acc[3][2] += a3 * b2; acc[3][3] += a3 * b3;
  }
  #pragma unroll
  for (int x = 0; x < 4; ++x)
    #pragma unroll
    for (int y = 0; y < 4; ++y)
      T2[(size_t)bh * 4096 + (ri + x) * 64 + ci + y] = acc[x][y];
}

// ---------------------------------------------------------------------------
// K10: conv residual -> d_out. REVERTED to the R2 version (known 154us,
// VALUBusy 79%, VGPR 92). R5's u=8 + (256,2) variant regressed to ~204us
// (2 waves/SIMD could not hide the 40-load bursts); R3/R4's no-bounds
// variant spilled (64-VGPR default cap on this toolchain).
// ---------------------------------------------------------------------------
__global__ void __launch_bounds__(256) k_conv(const float* __restrict__ v,
                                              const float* __restrict__ cw,
                                              float* __restrict__ out) {
  __shared__ float wl[2112]; // [i][t][o] = i*264 + t*8 + o
  int tid = threadIdx.x;
  for (int idx = tid; idx < 2112; idx += 256) {
    int o = idx / 264, r = idx % 264, i = r / 33, t = r % 33;
    wl[i * 264 + t * 8 + o] = cw[idx];
  }
  __syncthreads();
  int d = tid & 63;
  int sub = tid >> 6;                        // 0..3
  int b = blockIdx.x >> 8;                   // 8 b
  int n0 = (blockIdx.x & 255) * 16 + sub * 4;
  float acc[8][4] = {};                      // [o][u]
  for (int i = 0; i < 8; ++i) {
    const float* vp = v + ((size_t)(b * 8 + i) * cN) * 64 + d;
    float win[36];
    #pragma unroll
    for (int t = 0; t < 36; ++t) {
      int nn = n0 - 16 + t;
      win[t] = (nn >= 0 && nn < cN) ? vp[(size_t)nn * 64] : 0.f;
    }
    #pragma unroll
    for (int t = 0; t < 33; ++t) {
      float4 w0 = *(const float4*)&wl[i * 264 + t * 8];
      float4 w1 = *(const float4*)&wl[i * 264 + t * 8 + 4];
      #pragma unroll
      for (int u = 0; u < 4; ++u) {
        float val = win[t + u];
        acc[0][u] += val * w0.x; acc[1][u] += val * w0.y;
        acc[2][u] += val * w0.z; acc[3][u] += val * w0.w;
        acc[4][u] += val * w1.x; acc[5][u] += val * w1.y;
        acc[6][u] += val * w1.z; acc[7][u] += val * w1.w;
      }
    }
  }
  #pragma unroll
  for (int o = 0; o < 8; ++o) {
    float* op = out + ((size_t)(b * 8 + o) * cN + n0) * 64 + d;
    #pragma unroll
    for (int u = 0; u < 4; ++u) op[(size_t)u * 64] = acc[o][u];
  }
}

// ---------------------------------------------------------------------------
// K11: fused sim1 chain (R6: 4i x 4j).
// R5 counters (2i x 4j): 211us, bank-conflict 0, VALUBusy 32%, no spill.
// LDS-pipe floor: 96 b128/wave-phase (1152 cyc) per 1024 FMA-cyc ->
// 2blk x 8w x 16ph x 1152 = 295K cyc/CU = 123us; rest is overhead.
// Fix: 4 rows/thread (256 threads, 16 groups x 4 rows): per phase
// 4 kv + 16 af = 128 b128 per 2048 FMA-cyc (ratio 1.125 -> 0.75) ->
// floor 82us. sim[8][4][4]=128 VGPR; (256,2) = 2blk/CU x 4 waves =
// 2 waves/SIMD -> 256-VGPR cap (launch-bounds rule from R1/R4).
// LDS unchanged (70KB, 2 blk/CU). Spill sentinel: FETCH must stay ~74MB.
// ---------------------------------------------------------------------------
__device__ __forceinline__ void dot64_4x4(const float* __restrict__ A,   // row r0, pitch 68
                                          const float* __restrict__ Bm, int jb,
                                          float s[4][4]) {
  #pragma unroll
  for (int dc = 0; dc < 16; ++dc) {
    float4 kv0 = *(const float4*)&Bm[(dc * 4 + 0) * 68 + jb];
    float4 kv1 = *(const float4*)&Bm[(dc * 4 + 1) * 68 + jb];
    float4 kv2 = *(const float4*)&Bm[(dc * 4 + 2) * 68 + jb];
    float4 kv3 = *(const float4*)&Bm[(dc * 4 + 3) * 68 + jb];
    #pragma unroll
    for (int r = 0; r < 4; ++r) {
      float4 af = *(const float4*)&A[r * 68 + dc * 4];
      s[r][0] += af.x * kv0.x; s[r][1] += af.x * kv0.y; s[r][2] += af.x * kv0.z; s[r][3] += af.x * kv0.w;
      s[r][0] += af.y * kv1.x; s[r][1] += af.y * kv1.y; s[r][2] += af.y * kv1.z; s[r][3] += af.y * kv1.w;
      s[r][0] += af.z * kv2.x; s[r][1] += af.z * kv2.y; s[r][2] += af.z * kv2.z; s[r][3] += af.z * kv2.w;
      s[r][0] += af.w * kv3.x; s[r][1] += af.w * kv3.y; s[r][2] += af.w * kv3.z; s[r][3] += af.w * kv3.w;
    }
  }
}

// Stage one 64x64 tile (1024 float4) into LDS [64][68], 256 threads.
__device__ __forceinline__ void stage_tile(float* __restrict__ dst,
                                           const float4* __restrict__ src, int tid) {
  int sr = tid >> 4, sc = (tid & 15) * 4;
  float4 a = src[tid];
  float4 b = src[tid + 256];
  float4 c = src[tid + 512];
  float4 d = src[tid + 768];
  *(float4*)&dst[sr * 68 + sc] = a;
  *(float4*)&dst[(16 + sr) * 68 + sc] = b;
  *(float4*)&dst[(32 + sr) * 68 + sc] = c;
  *(float4*)&dst[(48 + sr) * 68 + sc] = d;
}

__global__ void __launch_bounds__(256, 2) k_final(const float* __restrict__ q,
                                                  const float* __restrict__ klT,
                                                  const float* __restrict__ T2,
                                                  const float* __restrict__ Wsim1,
                                                  const float* __restrict__ Wattn1,
                                                  float* __restrict__ out) {
  // 4 buffers of 64x68: Q0 | Q1 | L0 | L1. Phase1: Q=q-tile, L=klT-tile,
  // parity h&1. Phase2: Q=P-tile, L=T2-tile, parity k2&1. ~70KB -> 2 blk/CU.
  __shared__ float SB[4 * 64 * 68];
  __shared__ float ws1[64], wa1[64];
  constexpr int PITCH = 68, BUF = 64 * 68;
  int b = blockIdx.x >> 6, i0 = (blockIdx.x & 63) * 64;
  int tid = threadIdx.x;
  if (tid < 64) { ws1[tid] = Wsim1[tid]; wa1[tid] = Wattn1[tid]; }
  int jb = (tid & 15) * 4, r0 = (tid >> 4) * 4;

  float sim[8][4][4] = {};   // [k][row][col] = 128 VGPR

  const float4* qb = (const float4*)(q + ((size_t)(b * 8) * cN + i0) * 64);
  const float4* kb = (const float4*)(klT + (size_t)(b * 8) * 4096);
  const float4* tb = (const float4*)(T2 + (size_t)(b * 8) * 4096);

  // prologue: h=0 tiles into buffer 0
  stage_tile(SB + 0 * BUF, qb, tid);
  stage_tile(SB + 2 * BUF, kb, tid);
  __syncthreads();

  // ---- phase 1: h = 0..6 (stage h+1 at top, compute h, barrier) ----
  for (int h = 0; h < 7; ++h) {
    int p = h & 1, pn = p ^ 1;
    stage_tile(SB + pn * BUF, qb + (size_t)(h + 1) * 65536, tid);
    stage_tile(SB + (2 + pn) * BUF, kb + (size_t)(h + 1) * 1024, tid);
    float s[4][4] = {};
    dot64_4x4(SB + p * BUF + r0 * PITCH, SB + (2 + p) * BUF, jb, s);
    #pragma unroll
    for (int kq = 0; kq < 8; ++kq) {
      float wv = ws1[h * 8 + kq];
      #pragma unroll
      for (int r = 0; r < 4; ++r)
        #pragma unroll
        for (int c = 0; c < 4; ++c) sim[kq][r][c] += wv * s[r][c];
    }
    __syncthreads();
  }

  // ---- h = 7 (p = 1): stage T2[0] -> L0, compute, softmax+mix, P0 -> Q0 ----
  {
    stage_tile(SB + 2 * BUF, tb, tid);
    float s[4][4] = {};
    dot64_4x4(SB + 1 * BUF + r0 * PITCH, SB + 3 * BUF, jb, s);
    #pragma unroll
    for (int kq = 0; kq < 8; ++kq) {
      float wv = ws1[56 + kq];
      #pragma unroll
      for (int r = 0; r < 4; ++r)
        #pragma unroll
        for (int c = 0; c < 4; ++c) sim[kq][r][c] += wv * s[r][c];
    }
    // softmax over j=64 (16 lanes x 4 cols) for each of the 4 rows
    #pragma unroll
    for (int kq = 0; kq < 8; ++kq) {
      #pragma unroll
      for (int r = 0; r < 4; ++r) {
        float mx = fmaxf(fmaxf(sim[kq][r][0], sim[kq][r][1]),
                         fmaxf(sim[kq][r][2], sim[kq][r][3]));
        mx = fmaxf(mx, __shfl_xor(mx, 1)); mx = fmaxf(mx, __shfl_xor(mx, 2));
        mx = fmaxf(mx, __shfl_xor(mx, 4)); mx = fmaxf(mx, __shfl_xor(mx, 8));
        float sm = 0.f;
        #pragma unroll
        for (int c = 0; c < 4; ++c) {
          sim[kq][r][c] = expf(sim[kq][r][c] - mx);
          sm += sim[kq][r][c];
        }
        sm += __shfl_xor(sm, 1); sm += __shfl_xor(sm, 2);
        sm += __shfl_xor(sm, 4); sm += __shfl_xor(sm, 8);
        float inv = 1.0f / sm;
        #pragma unroll
        for (int c = 0; c < 4; ++c) sim[kq][r][c] *= inv;
      }
    }
    // Wattn1 mix in registers
    #pragma unroll
    for (int r = 0; r < 4; ++r)
      #pragma unroll
      for (int c = 0; c < 4; ++c) {
        float t[8];
        #pragma unroll
        for (int k2 = 0; k2 < 8; ++k2) {
          float a = 0.f;
          #pragma unroll
          for (int kk = 0; kk < 8; ++kk) a += sim[kk][r][c] * wa1[kk * 8 + k2];
          t[k2] = a;
        }
        #pragma unroll
        for (int k2 = 0; k2 < 8; ++k2) sim[k2][r][c] = t[k2];
      }
    // P[0] -> Q0
    #pragma unroll
    for (int r = 0; r < 4; ++r)
      *(float4*)&SB[(r0 + r) * PITCH + jb] =
          make_float4(sim[0][r][0], sim[0][r][1], sim[0][r][2], sim[0][r][3]);
    __syncthreads();
  }

  // ---- phase 2: out[k2] += P[k2] @ T2[k2]; immediate global RMW per k2 ----
  #pragma unroll
  for (int k2 = 0; k2 < 8; ++k2) {
    int p = k2 & 1, pn = p ^ 1;
    if (k2 < 7) {
      stage_tile(SB + (2 + pn) * BUF, tb + (size_t)(k2 + 1) * 1024, tid);
      #pragma unroll
      for (int r = 0; r < 4; ++r)
        *(float4*)&SB[pn * BUF + (r0 + r) * PITCH + jb] =
            make_float4(sim[k2 + 1][r][0], sim[k2 + 1][r][1],
                        sim[k2 + 1][r][2], sim[k2 + 1][r][3]);
    }
    float o[4][4] = {};
    dot64_4x4(SB + p * BUF + r0 * PITCH, SB + (2 + p) * BUF, jb, o);
    #pragma unroll
    for (int r = 0; r < 4; ++r) {
      float* op = out + ((size_t)(b * 8 + k2) * cN + i0 + r0 + r) * 64 + jb;
      float4 e = *(float4*)op;
      e.x += o[r][0]; e.y += o[r][1]; e.z += o[r][2]; e.w += o[r][3];
      *(float4*)op = e;
    }
    if (k2 < 7) __syncthreads();
  }
}

// ---------------------------------------------------------------------------
extern "C" void kernel_launch(void* const* d_in, const int* in_sizes, int n_in,
                              void* d_out, int out_size, void* d_ws, size_t ws_size,
                              hipStream_t stream) {
  const float* q = (const float*)d_in[0];
  const float* k = (const float*)d_in[1];
  const float* v = (const float*)d_in[2];
  const float* Wsim1 = (const float*)d_in[3];
  const float* Wsim2 = (const float*)d_in[4];
  const float* Wsim3 = (const float*)d_in[5];
  const float* Wattn1 = (const float*)d_in[6];
  const float* Wattn2 = (const float*)d_in[7];
  const float* Wattn3 = (const float*)d_in[8];
  const float* cw = (const float*)d_in[9];
  float* out = (float*)d_out;
  float* ws = (float*)d_ws;

  float* ql       = ws + 0;
  float* kl       = ws + 262144;
  float* attn2    = ws + 524288;
  float* attn2inv = ws + 786432;
  float* attn2m   = ws + 1048576;
  float* T2       = ws + 1310720;
  float* rmax     = ws + 1572864;
  float* rsum     = ws + 1576960;
  unsigned int* scal = (unsigned int*)(ws + 1581056);
  float* T3p      = ws + 1581120;  // 4 * 64 * 4096 = 1,048,576 floats
  // d_out (exactly B*H*64*N floats) doubles as sim3m scratch; fully consumed
  // by k_t3 before k_conv overwrites d_out with the conv residual.
  float* sim3m = out;

  hipMemsetAsync(scal, 0, 8, stream);
  k_landmarks<<<dim3(4096), dim3(64), 0, stream>>>(q, k, ql, kl);
  k_sim2<<<dim3(64), dim3(256), 0, stream>>>(ql, kl, Wsim2, attn2, scal);
  // kl's last row-major reader is k_sim2; transpose it in place to [d][m]
  // so k_final can stage it linearly (conflict-free).
  k_klT<<<dim3(64), dim3(256), 0, stream>>>(kl);
  k_pinv<<<dim3(64), dim3(256), 0, stream>>>(attn2, attn2inv, scal);
  k_mix_heads64<<<dim3(64), dim3(256), 0, stream>>>(attn2inv, Wattn2, attn2m);
  k_sim3<<<dim3(1024), dim3(512), 0, stream>>>(ql, k, Wsim3, sim3m);
  k_stats3<<<dim3(4096), dim3(256), 0, stream>>>(sim3m, rmax, rsum);
  k_smx3<<<dim3(8192), dim3(256), 0, stream>>>(sim3m, rmax, rsum, Wattn3);
  k_t3<<<dim3(256), dim3(256), 0, stream>>>(sim3m, v, T3p);
  k_t2<<<dim3(64), dim3(256), 0, stream>>>(attn2m, T3p, T2);
  k_conv<<<dim3(2048), dim3(256), 0, stream>>>(v, cw, out);
  k_final<<<dim3(512), dim3(256), 0, stream>>>(q, kl, T2, Wsim1, Wattn1, out);
}

// Round 7
// 914.837 us; speedup vs baseline: 1.2590x; 1.2590x over previous
//
#include <hip/hip_runtime.h>
#include <cstddef>
#include <cstdint>

// Problem constants
constexpr int cB = 8, cH = 8, cN = 4096, cD = 64, cM = 64, cL = 64;

// ---------------------------------------------------------------------------
// K1: landmarks  q_l/k_l[bh][m][d] = mean over l=64 tokens
// ---------------------------------------------------------------------------
__global__ void k_landmarks(const float* __restrict__ q, const float* __restrict__ k,
                            float* __restrict__ ql, float* __restrict__ kl) {
  int bm = blockIdx.x;          // BH*M = 4096
  int bh = bm >> 6, m = bm & 63;
  int d = threadIdx.x;          // 64
  size_t base = ((size_t)bh * cN + (size_t)m * cL) * cD + d;
  float sq = 0.f, sk = 0.f;
  for (int t = 0; t < cL; ++t) {
    sq += q[base + (size_t)t * cD];
    sk += k[base + (size_t)t * cD];
  }
  size_t ob = ((size_t)bh * cM + m) * cD + d;
  ql[ob] = sq * (1.0f / cL);
  kl[ob] = sk * (1.0f / cL);
}

// ---------------------------------------------------------------------------
// K2: sim2 = q_l k_l^T, mix heads (Wsim2), softmax rows, write attn2.
// Also atomicMax of global col-sum max (scal[0]) and row-sum max (scal[1]).
// ---------------------------------------------------------------------------
__global__ void __launch_bounds__(256) k_sim2(const float* __restrict__ ql,
                                              const float* __restrict__ kl,
                                              const float* __restrict__ Wsim2,
                                              float* __restrict__ attn2,
                                              unsigned int* __restrict__ scal) {
  __shared__ float qs[64][65];
  __shared__ float ks[64][65];
  __shared__ float acc[64 * 65];
  int b = blockIdx.x >> 3, kk = blockIdx.x & 7;
  int tid = threadIdx.x;
  for (int idx = tid; idx < 64 * 64; idx += 256)
    acc[(idx >> 6) * 65 + (idx & 63)] = 0.f;
  int ri = (tid >> 4) * 4, ci = (tid & 15) * 4;
  for (int h = 0; h < 8; ++h) {
    __syncthreads();
    const float* qg = ql + (size_t)(b * 8 + h) * 4096;
    const float* kg = kl + (size_t)(b * 8 + h) * 4096;
    for (int idx = tid; idx < 4096; idx += 256) {
      qs[idx >> 6][idx & 63] = qg[idx];
      ks[idx >> 6][idx & 63] = kg[idx];
    }
    __syncthreads();
    float w = Wsim2[h * 8 + kk];
    float s[4][4] = {};
    for (int d = 0; d < 64; ++d) {
      float a0 = qs[ri][d], a1 = qs[ri + 1][d], a2 = qs[ri + 2][d], a3 = qs[ri + 3][d];
      float b0 = ks[ci][d], b1 = ks[ci + 1][d], b2 = ks[ci + 2][d], b3 = ks[ci + 3][d];
      s[0][0] += a0 * b0; s[0][1] += a0 * b1; s[0][2] += a0 * b2; s[0][3] += a0 * b3;
      s[1][0] += a1 * b0; s[1][1] += a1 * b1; s[1][2] += a1 * b2; s[1][3] += a1 * b3;
      s[2][0] += a2 * b0; s[2][1] += a2 * b1; s[2][2] += a2 * b2; s[2][3] += a2 * b3;
      s[3][0] += a3 * b0; s[3][1] += a3 * b1; s[3][2] += a3 * b2; s[3][3] += a3 * b3;
    }
    #pragma unroll
    for (int x = 0; x < 4; ++x)
      #pragma unroll
      for (int y = 0; y < 4; ++y)
        acc[(ri + x) * 65 + ci + y] += w * s[x][y];
  }
  __syncthreads();
  if (tid < 64) {
    float mx = -1e30f;
    for (int j = 0; j < 64; ++j) mx = fmaxf(mx, acc[tid * 65 + j]);
    float s = 0.f;
    for (int j = 0; j < 64; ++j) {
      float e = expf(acc[tid * 65 + j] - mx);
      acc[tid * 65 + j] = e;
      s += e;
    }
    float inv = 1.0f / s;
    float rs = 0.f;
    for (int j = 0; j < 64; ++j) {
      float p = acc[tid * 65 + j] * inv;
      acc[tid * 65 + j] = p;
      rs += p;
    }
    atomicMax(scal + 1, __float_as_uint(rs));
  }
  __syncthreads();
  if (tid < 64) {
    float cs = 0.f;
    for (int i = 0; i < 64; ++i) cs += acc[i * 65 + tid];
    atomicMax(scal + 0, __float_as_uint(cs));
  }
  __syncthreads();
  float* op = attn2 + (size_t)(b * 8 + kk) * 4096;
  for (int idx = tid; idx < 4096; idx += 256)
    op[idx] = acc[(idx >> 6) * 65 + (idx & 63)];
}

// ---------------------------------------------------------------------------
// K2b: in-place transpose of kl [bh][m][d] -> [bh][d][m].
// ---------------------------------------------------------------------------
__global__ void k_klT(float* __restrict__ kl) {
  __shared__ float t[64 * 65];
  int bh = blockIdx.x, tid = threadIdx.x;
  float* p = kl + (size_t)bh * 4096;
  for (int idx = tid; idx < 4096; idx += 256)
    t[(idx >> 6) * 65 + (idx & 63)] = p[idx];
  __syncthreads();
  for (int idx = tid; idx < 4096; idx += 256)
    p[idx] = t[(idx & 63) * 65 + (idx >> 6)];
}

// ---------------------------------------------------------------------------
// K3: Moore-Penrose pinv, 6 Newton-Schulz iterations in LDS, per (b,k) block.
// ---------------------------------------------------------------------------
__device__ __forceinline__ void mm64(float* __restrict__ Dst, const float* S,
                                     float c0, float c1, const float* __restrict__ P,
                                     const float* __restrict__ Q, int tid) {
  int ri = (tid >> 4) * 4, ci = (tid & 15) * 4;
  float s[4][4] = {};
  for (int k = 0; k < 64; ++k) {
    float a0 = P[(ri + 0) * 65 + k], a1 = P[(ri + 1) * 65 + k];
    float a2 = P[(ri + 2) * 65 + k], a3 = P[(ri + 3) * 65 + k];
    float b0 = Q[k * 65 + ci + 0], b1 = Q[k * 65 + ci + 1];
    float b2 = Q[k * 65 + ci + 2], b3 = Q[k * 65 + ci + 3];
    s[0][0] += a0 * b0; s[0][1] += a0 * b1; s[0][2] += a0 * b2; s[0][3] += a0 * b3;
    s[1][0] += a1 * b0; s[1][1] += a1 * b1; s[1][2] += a1 * b2; s[1][3] += a1 * b3;
    s[2][0] += a2 * b0; s[2][1] += a2 * b1; s[2][2] += a2 * b2; s[2][3] += a2 * b3;
    s[3][0] += a3 * b0; s[3][1] += a3 * b1; s[3][2] += a3 * b2; s[3][3] += a3 * b3;
  }
  #pragma unroll
  for (int x = 0; x < 4; ++x)
    #pragma unroll
    for (int y = 0; y < 4; ++y) {
      float r = c1 * s[x][y];
      if (S) r += c0 * S[(ri + x) * 65 + ci + y];
      Dst[(ri + x) * 65 + ci + y] = r;
    }
}

__global__ void __launch_bounds__(256) k_pinv(const float* __restrict__ attn2,
                                              float* __restrict__ attn2inv,
                                              const unsigned int* __restrict__ scal) {
  __shared__ float bufs[5][64 * 65];
  float* X = bufs[0];
  float* Z = bufs[1];
  float* T1 = bufs[2];
  float* T2 = bufs[3];
  float* T3 = bufs[4];
  int tid = threadIdx.x;
  const float* xg = attn2 + (size_t)blockIdx.x * 4096;
  for (int idx = tid; idx < 4096; idx += 256)
    X[(idx >> 6) * 65 + (idx & 63)] = xg[idx];
  float denom = __uint_as_float(scal[0]) * __uint_as_float(scal[1]);
  float invd = 1.0f / denom;
  __syncthreads();
  for (int idx = tid; idx < 4096; idx += 256) {
    int i = idx >> 6, j = idx & 63;
    Z[i * 65 + j] = X[j * 65 + i] * invd;
  }
  __syncthreads();
  for (int it = 0; it < 6; ++it) {
    mm64(T1, nullptr, 0.f, 1.f, X, Z, tid);          __syncthreads();
    mm64(T2, T1, 7.f, -1.f, T1, T1, tid);            __syncthreads();
    mm64(T3, T1, 15.f, -1.f, T1, T2, tid);           __syncthreads();
    mm64(T2, Z, 13.f * 0.25f, -0.25f, Z, T3, tid);   __syncthreads();
    float* tmp = Z; Z = T2; T2 = tmp;
  }
  float* og = attn2inv + (size_t)blockIdx.x * 4096;
  for (int idx = tid; idx < 4096; idx += 256)
    og[idx] = Z[(idx >> 6) * 65 + (idx & 63)];
}

// ---------------------------------------------------------------------------
// K4: head-mix of 64x64 mats: out[b][k2] = sum_k in[b][k] * W[k][k2]
// ---------------------------------------------------------------------------
__global__ void k_mix_heads64(const float* __restrict__ in, const float* __restrict__ W,
                              float* __restrict__ out) {
  int b = blockIdx.x >> 3, k2 = blockIdx.x & 7;
  int tid = threadIdx.x;
  __shared__ float w[8];
  if (tid < 8) w[tid] = W[tid * 8 + k2];
  __syncthreads();
  const float* ib = in + (size_t)b * 8 * 4096;
  float* ob = out + ((size_t)b * 8 + k2) * 4096;
  for (int idx = tid; idx < 4096; idx += 256) {
    float s = 0.f;
    #pragma unroll
    for (int k = 0; k < 8; ++k) s += ib[(size_t)k * 4096 + idx] * w[k];
    ob[idx] = s;
  }
}

// ---------------------------------------------------------------------------
// K5: sim3m[b][k][i][j] = sum_h Wsim3[h][k]*(q_l[b,h,i,:].k[b,h,j,:])
// ---------------------------------------------------------------------------
__global__ void __launch_bounds__(512) k_sim3(const float* __restrict__ ql,
                                              const float* __restrict__ kg,
                                              const float* __restrict__ Wsim3,
                                              float* __restrict__ sim3m) {
  __shared__ float qls[64 * 65];   // [i][d] pitch 65
  __shared__ float ksT[64 * 36];   // [d][j] pitch 36 (16B-aligned float4 rows)
  __shared__ float w3[64];
  int b = blockIdx.x >> 7, jt = blockIdx.x & 127;
  int j0 = jt * 32, tid = threadIdx.x;
  if (tid < 64) w3[tid] = Wsim3[tid];
  int i = tid >> 3, jb = (tid & 7) * 4;
  float acc[8][4] = {};
  for (int h = 0; h < 8; ++h) {
    __syncthreads();
    const float* qg = ql + (size_t)(b * 8 + h) * 4096;
    for (int idx = tid; idx < 4096; idx += 512)
      qls[(idx >> 6) * 65 + (idx & 63)] = qg[idx];
    const float* kp = kg + ((size_t)(b * 8 + h) * cN + j0) * 64;
    for (int idx = tid; idx < 2048; idx += 512) {
      int j = idx >> 6, d = idx & 63;
      ksT[d * 36 + j] = kp[idx];
    }
    __syncthreads();
    float s[4] = {};
    for (int d = 0; d < 64; ++d) {
      float a = qls[i * 65 + d];
      float4 kv = *(const float4*)&ksT[d * 36 + jb];
      s[0] += a * kv.x; s[1] += a * kv.y; s[2] += a * kv.z; s[3] += a * kv.w;
    }
    #pragma unroll
    for (int k = 0; k < 8; ++k) {
      float w = w3[h * 8 + k];
      #pragma unroll
      for (int c = 0; c < 4; ++c) acc[k][c] += w * s[c];
    }
  }
  #pragma unroll
  for (int k = 0; k < 8; ++k) {
    float* op = sim3m + ((size_t)((b * 8 + k) * 64 + i)) * cN + j0 + jb;
    *(float4*)op = make_float4(acc[k][0], acc[k][1], acc[k][2], acc[k][3]);
  }
}

// ---------------------------------------------------------------------------
// K6: row stats for softmax over j=4096: one block per (b,k,i) row.
// ---------------------------------------------------------------------------
__global__ void k_stats3(const float* __restrict__ sim3m, float* __restrict__ rmax,
                         float* __restrict__ rsum) {
  int row = blockIdx.x; // 4096
  const float* rp = sim3m + (size_t)row * cN;
  int tid = threadIdx.x;
  float vv[16];
  float mx = -1e30f;
  #pragma unroll
  for (int t = 0; t < 16; ++t) {
    vv[t] = rp[tid + t * 256];
    mx = fmaxf(mx, vv[t]);
  }
  __shared__ float red[8];
  for (int off = 32; off > 0; off >>= 1) mx = fmaxf(mx, __shfl_down(mx, off));
  if ((tid & 63) == 0) red[tid >> 6] = mx;
  __syncthreads();
  mx = fmaxf(fmaxf(red[0], red[1]), fmaxf(red[2], red[3]));
  float s = 0.f;
  #pragma unroll
  for (int t = 0; t < 16; ++t) s += expf(vv[t] - mx);
  for (int off = 32; off > 0; off >>= 1) s += __shfl_down(s, off);
  __syncthreads();
  if ((tid & 63) == 0) red[4 + (tid >> 6)] = s;
  __syncthreads();
  if (tid == 0) {
    rmax[row] = mx;
    rsum[row] = red[4] + red[5] + red[6] + red[7];
  }
}

// ---------------------------------------------------------------------------
// K7: in-place softmax + Wattn3 head-mix on sim3m, register-resident.
// ---------------------------------------------------------------------------
__global__ void __launch_bounds__(256) k_smx3(float* __restrict__ sim3m,
                                              const float* __restrict__ rmax,
                                              const float* __restrict__ rsum,
                                              const float* __restrict__ Wattn3) {
  __shared__ float w[64];
  int tid = threadIdx.x;
  if (tid < 64) w[tid] = Wattn3[tid];
  __syncthreads();
  int gid = blockIdx.x * 256 + tid;   // 2^21 = 8b * 64i * 4096j
  int j = gid & 4095;
  int i = (gid >> 12) & 63;
  int b = gid >> 18;
  float p[8];
  #pragma unroll
  for (int k = 0; k < 8; ++k) {
    int row = (b * 8 + k) * 64 + i;
    p[k] = expf(sim3m[(size_t)row * cN + j] - rmax[row]) / rsum[row];
  }
  #pragma unroll
  for (int k2 = 0; k2 < 8; ++k2) {
    float t = 0.f;
    #pragma unroll
    for (int k = 0; k < 8; ++k) t += p[k] * w[k * 8 + k2];
    int row = (b * 8 + k2) * 64 + i;
    sim3m[(size_t)row * cN + j] = t;
  }
}

// ---------------------------------------------------------------------------
// K8: T3 partials: T3p[c][bh] = attn3f[bh][:, cchunk] @ v[bh][cchunk, :]
// ---------------------------------------------------------------------------
__global__ void __launch_bounds__(256) k_t3(const float* __restrict__ attn3f,
                                            const float* __restrict__ v,
                                            float* __restrict__ T3p) {
  __shared__ float As[64][65];
  __shared__ float Vs[64][68];
  int bh = blockIdx.x >> 2, chunk = blockIdx.x & 3;
  int tid = threadIdx.x;
  int ri = (tid >> 4) * 4, ci = (tid & 15) * 4;
  float acc[4][4] = {};
  for (int jt = chunk * 16; jt < chunk * 16 + 16; ++jt) {
    __syncthreads();
    const float* ap = attn3f + (size_t)bh * 64 * cN + jt * 64;
    for (int idx = tid; idx < 4096; idx += 256)
      As[idx >> 6][idx & 63] = ap[(size_t)(idx >> 6) * cN + (idx & 63)];
    const float* vp = v + ((size_t)bh * cN + jt * 64) * 64;
    for (int idx = tid; idx < 4096; idx += 256)
      Vs[idx >> 6][idx & 63] = vp[idx];
    __syncthreads();
    for (int j = 0; j < 64; ++j) {
      float a0 = As[ri][j], a1 = As[ri + 1][j], a2 = As[ri + 2][j], a3 = As[ri + 3][j];
      float b0 = Vs[j][ci], b1 = Vs[j][ci + 1], b2 = Vs[j][ci + 2], b3 = Vs[j][ci + 3];
      acc[0][0] += a0 * b0; acc[0][1] += a0 * b1; acc[0][2] += a0 * b2; acc[0][3] += a0 * b3;
      acc[1][0] += a1 * b0; acc[1][1] += a1 * b1; acc[1][2] += a1 * b2; acc[1][3] += a1 * b3;
      acc[2][0] += a2 * b0; acc[2][1] += a2 * b1; acc[2][2] += a2 * b2; acc[2][3] += a2 * b3;
      acc[3][0] += a3 * b0; acc[3][1] += a3 * b1; acc[3][2] += a3 * b2; acc[3][3] += a3 * b3;
    }
  }
  float* op = T3p + ((size_t)chunk * 64 + bh) * 4096;
  #pragma unroll
  for (int x = 0; x < 4; ++x)
    #pragma unroll
    for (int y = 0; y < 4; ++y)
      op[(ri + x) * 64 + ci + y] = acc[x][y];
}

// ---------------------------------------------------------------------------
// K9: T2[bh] = attn2m[bh] @ (sum of 4 T3 partials). Block per bh.
// ---------------------------------------------------------------------------
__global__ void __launch_bounds__(256) k_t2(const float* __restrict__ attn2m,
                                            const float* __restrict__ T3p,
                                            float* __restrict__ T2) {
  __shared__ float As[64][65];
  __shared__ float Bs[64][68];
  int bh = blockIdx.x, tid = threadIdx.x;
  const float* ap = attn2m + (size_t)bh * 4096;
  for (int idx = tid; idx < 4096; idx += 256) {
    As[idx >> 6][idx & 63] = ap[idx];
    float s = 0.f;
    #pragma unroll
    for (int c = 0; c < 4; ++c) s += T3p[((size_t)c * 64 + bh) * 4096 + idx];
    Bs[idx >> 6][idx & 63] = s;
  }
  __syncthreads();
  int ri = (tid >> 4) * 4, ci = (tid & 15) * 4;
  float acc[4][4] = {};
  for (int j = 0; j < 64; ++j) {
    float a0 = As[ri][j], a1 = As[ri + 1][j], a2 = As[ri + 2][j], a3 = As[ri + 3][j];
    float b0 = Bs[j][ci], b1 = Bs[j][ci + 1], b2 = Bs[j][ci + 2], b3 = Bs[j][ci + 3];
    acc[0][0] += a0 * b0; acc[0][1] += a0 * b1; acc[0][2] += a0 * b2; acc[0][3] += a0 * b3;
    acc[1][0] += a1 * b0; acc[1][1] += a1 * b1; acc[1][2] += a1 * b2; acc[1][3] += a1 * b3;
    acc[2][0] += a2 * b0; acc[2][1] += a2 * b1; acc[2][2] += a2 * b2; acc[2][3] += a2 * b3;
    acc[3][0] += a3 * b0; acc[3][1] += a3 * b1; acc[3][2] += a3 * b2; acc[3][3] += a3 * b3;
  }
  #pragma unroll
  for (int x = 0; x < 4; ++x)
    #pragma unroll
    for (int y = 0; y < 4; ++y)
      T2[(size_t)bh * 4096 + (ri + x) * 64 + ci + y] = acc[x][y];
}

// ---------------------------------------------------------------------------
// K10: conv residual -> d_out (R2 version, known-good: 154us, VALUBusy 79%,
// VGPR 92). u=8 variants all lost: no-bounds -> 64-cap spill; (256,2) ->
// 2 waves/SIMD latency-starved.
// ---------------------------------------------------------------------------
__global__ void __launch_bounds__(256) k_conv(const float* __restrict__ v,
                                              const float* __restrict__ cw,
                                              float* __restrict__ out) {
  __shared__ float wl[2112]; // [i][t][o] = i*264 + t*8 + o
  int tid = threadIdx.x;
  for (int idx = tid; idx < 2112; idx += 256) {
    int o = idx / 264, r = idx % 264, i = r / 33, t = r % 33;
    wl[i * 264 + t * 8 + o] = cw[idx];
  }
  __syncthreads();
  int d = tid & 63;
  int sub = tid >> 6;                        // 0..3
  int b = blockIdx.x >> 8;                   // 8 b
  int n0 = (blockIdx.x & 255) * 16 + sub * 4;
  float acc[8][4] = {};                      // [o][u]
  for (int i = 0; i < 8; ++i) {
    const float* vp = v + ((size_t)(b * 8 + i) * cN) * 64 + d;
    float win[36];
    #pragma unroll
    for (int t = 0; t < 36; ++t) {
      int nn = n0 - 16 + t;
      win[t] = (nn >= 0 && nn < cN) ? vp[(size_t)nn * 64] : 0.f;
    }
    #pragma unroll
    for (int t = 0; t < 33; ++t) {
      float4 w0 = *(const float4*)&wl[i * 264 + t * 8];
      float4 w1 = *(const float4*)&wl[i * 264 + t * 8 + 4];
      #pragma unroll
      for (int u = 0; u < 4; ++u) {
        float val = win[t + u];
        acc[0][u] += val * w0.x; acc[1][u] += val * w0.y;
        acc[2][u] += val * w0.z; acc[3][u] += val * w0.w;
        acc[4][u] += val * w1.x; acc[5][u] += val * w1.y;
        acc[6][u] += val * w1.z; acc[7][u] += val * w1.w;
      }
    }
  }
  #pragma unroll
  for (int o = 0; o < 8; ++o) {
    float* op = out + ((size_t)(b * 8 + o) * cN + n0) * 64 + d;
    #pragma unroll
    for (int u = 0; u < 4; ++u) op[(size_t)u * 64] = acc[o][u];
  }
}

// ---------------------------------------------------------------------------
// K11: fused sim1 chain (R7: 4i x 4j, bare launch_bounds).
// R6: (256,2) pinned VGPR at 128 -> ~90 floats/thread spilled (FETCH +25MB,
// WRITE +49MB), 369us. Launch-bounds oracle on this toolchain: explicit 2nd
// arg pins a low cap [(512,4)->64, (512,2)->128, (256,2)->128]; BARE bounds
// let the allocator choose [(256)->92 in k_conv, (512)->up to 256 in the
// pre-session k_sim3 note]. Fix: __launch_bounds__(256) bare -> expect
// ~180-220 VGPR, no spill. LDS 70KB still caps at 2 blk/CU = 2 waves/SIMD.
// Tile math: per phase 4 kv + 16 af = 128 b128 per 2048 FMA-cyc (0.75 ratio
// vs 1.125 for 2i x 4j) -> LDS floor 82us.
// Spill sentinel: FETCH ~74MB / WRITE ~66MB. If VGPR still reads 128, the
// allocator has a hard preference and 4i x 4j is abandoned next round.
// ---------------------------------------------------------------------------
__device__ __forceinline__ void dot64_4x4(const float* __restrict__ A,   // row r0, pitch 68
                                          const float* __restrict__ Bm, int jb,
                                          float s[4][4]) {
  #pragma unroll
  for (int dc = 0; dc < 16; ++dc) {
    float4 kv0 = *(const float4*)&Bm[(dc * 4 + 0) * 68 + jb];
    float4 kv1 = *(const float4*)&Bm[(dc * 4 + 1) * 68 + jb];
    float4 kv2 = *(const float4*)&Bm[(dc * 4 + 2) * 68 + jb];
    float4 kv3 = *(const float4*)&Bm[(dc * 4 + 3) * 68 + jb];
    #pragma unroll
    for (int r = 0; r < 4; ++r) {
      float4 af = *(const float4*)&A[r * 68 + dc * 4];
      s[r][0] += af.x * kv0.x; s[r][1] += af.x * kv0.y; s[r][2] += af.x * kv0.z; s[r][3] += af.x * kv0.w;
      s[r][0] += af.y * kv1.x; s[r][1] += af.y * kv1.y; s[r][2] += af.y * kv1.z; s[r][3] += af.y * kv1.w;
      s[r][0] += af.z * kv2.x; s[r][1] += af.z * kv2.y; s[r][2] += af.z * kv2.z; s[r][3] += af.z * kv2.w;
      s[r][0] += af.w * kv3.x; s[r][1] += af.w * kv3.y; s[r][2] += af.w * kv3.z; s[r][3] += af.w * kv3.w;
    }
  }
}

// Stage one 64x64 tile (1024 float4) into LDS [64][68], 256 threads.
__device__ __forceinline__ void stage_tile(float* __restrict__ dst,
                                           const float4* __restrict__ src, int tid) {
  int sr = tid >> 4, sc = (tid & 15) * 4;
  float4 a = src[tid];
  float4 b = src[tid + 256];
  float4 c = src[tid + 512];
  float4 d = src[tid + 768];
  *(float4*)&dst[sr * 68 + sc] = a;
  *(float4*)&dst[(16 + sr) * 68 + sc] = b;
  *(float4*)&dst[(32 + sr) * 68 + sc] = c;
  *(float4*)&dst[(48 + sr) * 68 + sc] = d;
}

__global__ void __launch_bounds__(256) k_final(const float* __restrict__ q,
                                               const float* __restrict__ klT,
                                               const float* __restrict__ T2,
                                               const float* __restrict__ Wsim1,
                                               const float* __restrict__ Wattn1,
                                               float* __restrict__ out) {
  // 4 buffers of 64x68: Q0 | Q1 | L0 | L1. Phase1: Q=q-tile, L=klT-tile,
  // parity h&1. Phase2: Q=P-tile, L=T2-tile, parity k2&1. ~70KB -> 2 blk/CU.
  __shared__ float SB[4 * 64 * 68];
  __shared__ float ws1[64], wa1[64];
  constexpr int PITCH = 68, BUF = 64 * 68;
  int b = blockIdx.x >> 6, i0 = (blockIdx.x & 63) * 64;
  int tid = threadIdx.x;
  if (tid < 64) { ws1[tid] = Wsim1[tid]; wa1[tid] = Wattn1[tid]; }
  int jb = (tid & 15) * 4, r0 = (tid >> 4) * 4;

  float sim[8][4][4] = {};   // [k][row][col] = 128 VGPR

  const float4* qb = (const float4*)(q + ((size_t)(b * 8) * cN + i0) * 64);
  const float4* kb = (const float4*)(klT + (size_t)(b * 8) * 4096);
  const float4* tb = (const float4*)(T2 + (size_t)(b * 8) * 4096);

  // prologue: h=0 tiles into buffer 0
  stage_tile(SB + 0 * BUF, qb, tid);
  stage_tile(SB + 2 * BUF, kb, tid);
  __syncthreads();

  // ---- phase 1: h = 0..6 (stage h+1 at top, compute h, barrier) ----
  for (int h = 0; h < 7; ++h) {
    int p = h & 1, pn = p ^ 1;
    stage_tile(SB + pn * BUF, qb + (size_t)(h + 1) * 65536, tid);
    stage_tile(SB + (2 + pn) * BUF, kb + (size_t)(h + 1) * 1024, tid);
    float s[4][4] = {};
    dot64_4x4(SB + p * BUF + r0 * PITCH, SB + (2 + p) * BUF, jb, s);
    #pragma unroll
    for (int kq = 0; kq < 8; ++kq) {
      float wv = ws1[h * 8 + kq];
      #pragma unroll
      for (int r = 0; r < 4; ++r)
        #pragma unroll
        for (int c = 0; c < 4; ++c) sim[kq][r][c] += wv * s[r][c];
    }
    __syncthreads();
  }

  // ---- h = 7 (p = 1): stage T2[0] -> L0, compute, softmax+mix, P0 -> Q0 ----
  {
    stage_tile(SB + 2 * BUF, tb, tid);
    float s[4][4] = {};
    dot64_4x4(SB + 1 * BUF + r0 * PITCH, SB + 3 * BUF, jb, s);
    #pragma unroll
    for (int kq = 0; kq < 8; ++kq) {
      float wv = ws1[56 + kq];
      #pragma unroll
      for (int r = 0; r < 4; ++r)
        #pragma unroll
        for (int c = 0; c < 4; ++c) sim[kq][r][c] += wv * s[r][c];
    }
    // softmax over j=64 (16 lanes x 4 cols) for each of the 4 rows
    #pragma unroll
    for (int kq = 0; kq < 8; ++kq) {
      #pragma unroll
      for (int r = 0; r < 4; ++r) {
        float mx = fmaxf(fmaxf(sim[kq][r][0], sim[kq][r][1]),
                         fmaxf(sim[kq][r][2], sim[kq][r][3]));
        mx = fmaxf(mx, __shfl_xor(mx, 1)); mx = fmaxf(mx, __shfl_xor(mx, 2));
        mx = fmaxf(mx, __shfl_xor(mx, 4)); mx = fmaxf(mx, __shfl_xor(mx, 8));
        float sm = 0.f;
        #pragma unroll
        for (int c = 0; c < 4; ++c) {
          sim[kq][r][c] = expf(sim[kq][r][c] - mx);
          sm += sim[kq][r][c];
        }
        sm += __shfl_xor(sm, 1); sm += __shfl_xor(sm, 2);
        sm += __shfl_xor(sm, 4); sm += __shfl_xor(sm, 8);
        float inv = 1.0f / sm;
        #pragma unroll
        for (int c = 0; c < 4; ++c) sim[kq][r][c] *= inv;
      }
    }
    // Wattn1 mix in registers
    #pragma unroll
    for (int r = 0; r < 4; ++r)
      #pragma unroll
      for (int c = 0; c < 4; ++c) {
        float t[8];
        #pragma unroll
        for (int k2 = 0; k2 < 8; ++k2) {
          float a = 0.f;
          #pragma unroll
          for (int kk = 0; kk < 8; ++kk) a += sim[kk][r][c] * wa1[kk * 8 + k2];
          t[k2] = a;
        }
        #pragma unroll
        for (int k2 = 0; k2 < 8; ++k2) sim[k2][r][c] = t[k2];
      }
    // P[0] -> Q0
    #pragma unroll
    for (int r = 0; r < 4; ++r)
      *(float4*)&SB[(r0 + r) * PITCH + jb] =
          make_float4(sim[0][r][0], sim[0][r][1], sim[0][r][2], sim[0][r][3]);
    __syncthreads();
  }

  // ---- phase 2: out[k2] += P[k2] @ T2[k2]; immediate global RMW per k2 ----
  #pragma unroll
  for (int k2 = 0; k2 < 8; ++k2) {
    int p = k2 & 1, pn = p ^ 1;
    if (k2 < 7) {
      stage_tile(SB + (2 + pn) * BUF, tb + (size_t)(k2 + 1) * 1024, tid);
      #pragma unroll
      for (int r = 0; r < 4; ++r)
        *(float4*)&SB[pn * BUF + (r0 + r) * PITCH + jb] =
            make_float4(sim[k2 + 1][r][0], sim[k2 + 1][r][1],
                        sim[k2 + 1][r][2], sim[k2 + 1][r][3]);
    }
    float o[4][4] = {};
    dot64_4x4(SB + p * BUF + r0 * PITCH, SB + (2 + p) * BUF, jb, o);
    #pragma unroll
    for (int r = 0; r < 4; ++r) {
      float* op = out + ((size_t)(b * 8 + k2) * cN + i0 + r0 + r) * 64 + jb;
      float4 e = *(float4*)op;
      e.x += o[r][0]; e.y += o[r][1]; e.z += o[r][2]; e.w += o[r][3];
      *(float4*)op = e;
    }
    if (k2 < 7) __syncthreads();
  }
}

// ---------------------------------------------------------------------------
extern "C" void kernel_launch(void* const* d_in, const int* in_sizes, int n_in,
                              void* d_out, int out_size, void* d_ws, size_t ws_size,
                              hipStream_t stream) {
  const float* q = (const float*)d_in[0];
  const float* k = (const float*)d_in[1];
  const float* v = (const float*)d_in[2];
  const float* Wsim1 = (const float*)d_in[3];
  const float* Wsim2 = (const float*)d_in[4];
  const float* Wsim3 = (const float*)d_in[5];
  const float* Wattn1 = (const float*)d_in[6];
  const float* Wattn2 = (const float*)d_in[7];
  const float* Wattn3 = (const float*)d_in[8];
  const float* cw = (const float*)d_in[9];
  float* out = (float*)d_out;
  float* ws = (float*)d_ws;

  float* ql       = ws + 0;
  float* kl       = ws + 262144;
  float* attn2    = ws + 524288;
  float* attn2inv = ws + 786432;
  float* attn2m   = ws + 1048576;
  float* T2       = ws + 1310720;
  float* rmax     = ws + 1572864;
  float* rsum     = ws + 1576960;
  unsigned int* scal = (unsigned int*)(ws + 1581056);
  float* T3p      = ws + 1581120;  // 4 * 64 * 4096 = 1,048,576 floats
  // d_out (exactly B*H*64*N floats) doubles as sim3m scratch; fully consumed
  // by k_t3 before k_conv overwrites d_out with the conv residual.
  float* sim3m = out;

  hipMemsetAsync(scal, 0, 8, stream);
  k_landmarks<<<dim3(4096), dim3(64), 0, stream>>>(q, k, ql, kl);
  k_sim2<<<dim3(64), dim3(256), 0, stream>>>(ql, kl, Wsim2, attn2, scal);
  // kl's last row-major reader is k_sim2; transpose it in place to [d][m]
  // so k_final can stage it linearly (conflict-free).
  k_klT<<<dim3(64), dim3(256), 0, stream>>>(kl);
  k_pinv<<<dim3(64), dim3(256), 0, stream>>>(attn2, attn2inv, scal);
  k_mix_heads64<<<dim3(64), dim3(256), 0, stream>>>(attn2inv, Wattn2, attn2m);
  k_sim3<<<dim3(1024), dim3(512), 0, stream>>>(ql, k, Wsim3, sim3m);
  k_stats3<<<dim3(4096), dim3(256), 0, stream>>>(sim3m, rmax, rsum);
  k_smx3<<<dim3(8192), dim3(256), 0, stream>>>(sim3m, rmax, rsum, Wattn3);
  k_t3<<<dim3(256), dim3(256), 0, stream>>>(sim3m, v, T3p);
  k_t2<<<dim3(64), dim3(256), 0, stream>>>(attn2m, T3p, T2);
  k_conv<<<dim3(2048), dim3(256), 0, stream>>>(v, cw, out);
  k_final<<<dim3(512), dim3(256), 0, stream>>>(q, kl, T2, Wsim1, Wattn1, out);
}

// Round 8
// 838.128 us; speedup vs baseline: 1.3743x; 1.0915x over previous
//
#include <hip/hip_runtime.h>
#include <cstddef>
#include <cstdint>

// Problem constants
constexpr int cB = 8, cH = 8, cN = 4096, cD = 64, cM = 64, cL = 64;

// ---------------------------------------------------------------------------
// K1: landmarks  q_l/k_l[bh][m][d] = mean over l=64 tokens
// ---------------------------------------------------------------------------
__global__ void k_landmarks(const float* __restrict__ q, const float* __restrict__ k,
                            float* __restrict__ ql, float* __restrict__ kl) {
  int bm = blockIdx.x;          // BH*M = 4096
  int bh = bm >> 6, m = bm & 63;
  int d = threadIdx.x;          // 64
  size_t base = ((size_t)bh * cN + (size_t)m * cL) * cD + d;
  float sq = 0.f, sk = 0.f;
  for (int t = 0; t < cL; ++t) {
    sq += q[base + (size_t)t * cD];
    sk += k[base + (size_t)t * cD];
  }
  size_t ob = ((size_t)bh * cM + m) * cD + d;
  ql[ob] = sq * (1.0f / cL);
  kl[ob] = sk * (1.0f / cL);
}

// ---------------------------------------------------------------------------
// K2: sim2 = q_l k_l^T, mix heads (Wsim2), softmax rows, write attn2.
// Also atomicMax of global col-sum max (scal[0]) and row-sum max (scal[1]).
// ---------------------------------------------------------------------------
__global__ void __launch_bounds__(256) k_sim2(const float* __restrict__ ql,
                                              const float* __restrict__ kl,
                                              const float* __restrict__ Wsim2,
                                              float* __restrict__ attn2,
                                              unsigned int* __restrict__ scal) {
  __shared__ float qs[64][65];
  __shared__ float ks[64][65];
  __shared__ float acc[64 * 65];
  int b = blockIdx.x >> 3, kk = blockIdx.x & 7;
  int tid = threadIdx.x;
  for (int idx = tid; idx < 64 * 64; idx += 256)
    acc[(idx >> 6) * 65 + (idx & 63)] = 0.f;
  int ri = (tid >> 4) * 4, ci = (tid & 15) * 4;
  for (int h = 0; h < 8; ++h) {
    __syncthreads();
    const float* qg = ql + (size_t)(b * 8 + h) * 4096;
    const float* kg = kl + (size_t)(b * 8 + h) * 4096;
    for (int idx = tid; idx < 4096; idx += 256) {
      qs[idx >> 6][idx & 63] = qg[idx];
      ks[idx >> 6][idx & 63] = kg[idx];
    }
    __syncthreads();
    float w = Wsim2[h * 8 + kk];
    float s[4][4] = {};
    for (int d = 0; d < 64; ++d) {
      float a0 = qs[ri][d], a1 = qs[ri + 1][d], a2 = qs[ri + 2][d], a3 = qs[ri + 3][d];
      float b0 = ks[ci][d], b1 = ks[ci + 1][d], b2 = ks[ci + 2][d], b3 = ks[ci + 3][d];
      s[0][0] += a0 * b0; s[0][1] += a0 * b1; s[0][2] += a0 * b2; s[0][3] += a0 * b3;
      s[1][0] += a1 * b0; s[1][1] += a1 * b1; s[1][2] += a1 * b2; s[1][3] += a1 * b3;
      s[2][0] += a2 * b0; s[2][1] += a2 * b1; s[2][2] += a2 * b2; s[2][3] += a2 * b3;
      s[3][0] += a3 * b0; s[3][1] += a3 * b1; s[3][2] += a3 * b2; s[3][3] += a3 * b3;
    }
    #pragma unroll
    for (int x = 0; x < 4; ++x)
      #pragma unroll
      for (int y = 0; y < 4; ++y)
        acc[(ri + x) * 65 + ci + y] += w * s[x][y];
  }
  __syncthreads();
  if (tid < 64) {
    float mx = -1e30f;
    for (int j = 0; j < 64; ++j) mx = fmaxf(mx, acc[tid * 65 + j]);
    float s = 0.f;
    for (int j = 0; j < 64; ++j) {
      float e = expf(acc[tid * 65 + j] - mx);
      acc[tid * 65 + j] = e;
      s += e;
    }
    float inv = 1.0f / s;
    float rs = 0.f;
    for (int j = 0; j < 64; ++j) {
      float p = acc[tid * 65 + j] * inv;
      acc[tid * 65 + j] = p;
      rs += p;
    }
    atomicMax(scal + 1, __float_as_uint(rs));
  }
  __syncthreads();
  if (tid < 64) {
    float cs = 0.f;
    for (int i = 0; i < 64; ++i) cs += acc[i * 65 + tid];
    atomicMax(scal + 0, __float_as_uint(cs));
  }
  __syncthreads();
  float* op = attn2 + (size_t)(b * 8 + kk) * 4096;
  for (int idx = tid; idx < 4096; idx += 256)
    op[idx] = acc[(idx >> 6) * 65 + (idx & 63)];
}

// ---------------------------------------------------------------------------
// K2b: in-place transpose of kl [bh][m][d] -> [bh][d][m].
// ---------------------------------------------------------------------------
__global__ void k_klT(float* __restrict__ kl) {
  __shared__ float t[64 * 65];
  int bh = blockIdx.x, tid = threadIdx.x;
  float* p = kl + (size_t)bh * 4096;
  for (int idx = tid; idx < 4096; idx += 256)
    t[(idx >> 6) * 65 + (idx & 63)] = p[idx];
  __syncthreads();
  for (int idx = tid; idx < 4096; idx += 256)
    p[idx] = t[(idx & 63) * 65 + (idx >> 6)];
}

// ---------------------------------------------------------------------------
// K3: Moore-Penrose pinv, 6 Newton-Schulz iterations in LDS, per (b,k) block.
// ---------------------------------------------------------------------------
__device__ __forceinline__ void mm64(float* __restrict__ Dst, const float* S,
                                     float c0, float c1, const float* __restrict__ P,
                                     const float* __restrict__ Q, int tid) {
  int ri = (tid >> 4) * 4, ci = (tid & 15) * 4;
  float s[4][4] = {};
  for (int k = 0; k < 64; ++k) {
    float a0 = P[(ri + 0) * 65 + k], a1 = P[(ri + 1) * 65 + k];
    float a2 = P[(ri + 2) * 65 + k], a3 = P[(ri + 3) * 65 + k];
    float b0 = Q[k * 65 + ci + 0], b1 = Q[k * 65 + ci + 1];
    float b2 = Q[k * 65 + ci + 2], b3 = Q[k * 65 + ci + 3];
    s[0][0] += a0 * b0; s[0][1] += a0 * b1; s[0][2] += a0 * b2; s[0][3] += a0 * b3;
    s[1][0] += a1 * b0; s[1][1] += a1 * b1; s[1][2] += a1 * b2; s[1][3] += a1 * b3;
    s[2][0] += a2 * b0; s[2][1] += a2 * b1; s[2][2] += a2 * b2; s[2][3] += a2 * b3;
    s[3][0] += a3 * b0; s[3][1] += a3 * b1; s[3][2] += a3 * b2; s[3][3] += a3 * b3;
  }
  #pragma unroll
  for (int x = 0; x < 4; ++x)
    #pragma unroll
    for (int y = 0; y < 4; ++y) {
      float r = c1 * s[x][y];
      if (S) r += c0 * S[(ri + x) * 65 + ci + y];
      Dst[(ri + x) * 65 + ci + y] = r;
    }
}

__global__ void __launch_bounds__(256) k_pinv(const float* __restrict__ attn2,
                                              float* __restrict__ attn2inv,
                                              const unsigned int* __restrict__ scal) {
  __shared__ float bufs[5][64 * 65];
  float* X = bufs[0];
  float* Z = bufs[1];
  float* T1 = bufs[2];
  float* T2 = bufs[3];
  float* T3 = bufs[4];
  int tid = threadIdx.x;
  const float* xg = attn2 + (size_t)blockIdx.x * 4096;
  for (int idx = tid; idx < 4096; idx += 256)
    X[(idx >> 6) * 65 + (idx & 63)] = xg[idx];
  float denom = __uint_as_float(scal[0]) * __uint_as_float(scal[1]);
  float invd = 1.0f / denom;
  __syncthreads();
  for (int idx = tid; idx < 4096; idx += 256) {
    int i = idx >> 6, j = idx & 63;
    Z[i * 65 + j] = X[j * 65 + i] * invd;
  }
  __syncthreads();
  for (int it = 0; it < 6; ++it) {
    mm64(T1, nullptr, 0.f, 1.f, X, Z, tid);          __syncthreads();
    mm64(T2, T1, 7.f, -1.f, T1, T1, tid);            __syncthreads();
    mm64(T3, T1, 15.f, -1.f, T1, T2, tid);           __syncthreads();
    mm64(T2, Z, 13.f * 0.25f, -0.25f, Z, T3, tid);   __syncthreads();
    float* tmp = Z; Z = T2; T2 = tmp;
  }
  float* og = attn2inv + (size_t)blockIdx.x * 4096;
  for (int idx = tid; idx < 4096; idx += 256)
    og[idx] = Z[(idx >> 6) * 65 + (idx & 63)];
}

// ---------------------------------------------------------------------------
// K4: head-mix of 64x64 mats: out[b][k2] = sum_k in[b][k] * W[k][k2]
// ---------------------------------------------------------------------------
__global__ void k_mix_heads64(const float* __restrict__ in, const float* __restrict__ W,
                              float* __restrict__ out) {
  int b = blockIdx.x >> 3, k2 = blockIdx.x & 7;
  int tid = threadIdx.x;
  __shared__ float w[8];
  if (tid < 8) w[tid] = W[tid * 8 + k2];
  __syncthreads();
  const float* ib = in + (size_t)b * 8 * 4096;
  float* ob = out + ((size_t)b * 8 + k2) * 4096;
  for (int idx = tid; idx < 4096; idx += 256) {
    float s = 0.f;
    #pragma unroll
    for (int k = 0; k < 8; ++k) s += ib[(size_t)k * 4096 + idx] * w[k];
    ob[idx] = s;
  }
}

// ---------------------------------------------------------------------------
// K5: sim3m[b][k][i][j] = sum_h Wsim3[h][k]*(q_l[b,h,i,:].k[b,h,j,:])
// ---------------------------------------------------------------------------
__global__ void __launch_bounds__(512) k_sim3(const float* __restrict__ ql,
                                              const float* __restrict__ kg,
                                              const float* __restrict__ Wsim3,
                                              float* __restrict__ sim3m) {
  __shared__ float qls[64 * 65];   // [i][d] pitch 65
  __shared__ float ksT[64 * 36];   // [d][j] pitch 36 (16B-aligned float4 rows)
  __shared__ float w3[64];
  int b = blockIdx.x >> 7, jt = blockIdx.x & 127;
  int j0 = jt * 32, tid = threadIdx.x;
  if (tid < 64) w3[tid] = Wsim3[tid];
  int i = tid >> 3, jb = (tid & 7) * 4;
  float acc[8][4] = {};
  for (int h = 0; h < 8; ++h) {
    __syncthreads();
    const float* qg = ql + (size_t)(b * 8 + h) * 4096;
    for (int idx = tid; idx < 4096; idx += 512)
      qls[(idx >> 6) * 65 + (idx & 63)] = qg[idx];
    const float* kp = kg + ((size_t)(b * 8 + h) * cN + j0) * 64;
    for (int idx = tid; idx < 2048; idx += 512) {
      int j = idx >> 6, d = idx & 63;
      ksT[d * 36 + j] = kp[idx];
    }
    __syncthreads();
    float s[4] = {};
    for (int d = 0; d < 64; ++d) {
      float a = qls[i * 65 + d];
      float4 kv = *(const float4*)&ksT[d * 36 + jb];
      s[0] += a * kv.x; s[1] += a * kv.y; s[2] += a * kv.z; s[3] += a * kv.w;
    }
    #pragma unroll
    for (int k = 0; k < 8; ++k) {
      float w = w3[h * 8 + k];
      #pragma unroll
      for (int c = 0; c < 4; ++c) acc[k][c] += w * s[c];
    }
  }
  #pragma unroll
  for (int k = 0; k < 8; ++k) {
    float* op = sim3m + ((size_t)((b * 8 + k) * 64 + i)) * cN + j0 + jb;
    *(float4*)op = make_float4(acc[k][0], acc[k][1], acc[k][2], acc[k][3]);
  }
}

// ---------------------------------------------------------------------------
// K6: row stats for softmax over j=4096: one block per (b,k,i) row.
// ---------------------------------------------------------------------------
__global__ void k_stats3(const float* __restrict__ sim3m, float* __restrict__ rmax,
                         float* __restrict__ rsum) {
  int row = blockIdx.x; // 4096
  const float* rp = sim3m + (size_t)row * cN;
  int tid = threadIdx.x;
  float vv[16];
  float mx = -1e30f;
  #pragma unroll
  for (int t = 0; t < 16; ++t) {
    vv[t] = rp[tid + t * 256];
    mx = fmaxf(mx, vv[t]);
  }
  __shared__ float red[8];
  for (int off = 32; off > 0; off >>= 1) mx = fmaxf(mx, __shfl_down(mx, off));
  if ((tid & 63) == 0) red[tid >> 6] = mx;
  __syncthreads();
  mx = fmaxf(fmaxf(red[0], red[1]), fmaxf(red[2], red[3]));
  float s = 0.f;
  #pragma unroll
  for (int t = 0; t < 16; ++t) s += expf(vv[t] - mx);
  for (int off = 32; off > 0; off >>= 1) s += __shfl_down(s, off);
  __syncthreads();
  if ((tid & 63) == 0) red[4 + (tid >> 6)] = s;
  __syncthreads();
  if (tid == 0) {
    rmax[row] = mx;
    rsum[row] = red[4] + red[5] + red[6] + red[7];
  }
}

// ---------------------------------------------------------------------------
// K7: in-place softmax + Wattn3 head-mix on sim3m, register-resident.
// ---------------------------------------------------------------------------
__global__ void __launch_bounds__(256) k_smx3(float* __restrict__ sim3m,
                                              const float* __restrict__ rmax,
                                              const float* __restrict__ rsum,
                                              const float* __restrict__ Wattn3) {
  __shared__ float w[64];
  int tid = threadIdx.x;
  if (tid < 64) w[tid] = Wattn3[tid];
  __syncthreads();
  int gid = blockIdx.x * 256 + tid;   // 2^21 = 8b * 64i * 4096j
  int j = gid & 4095;
  int i = (gid >> 12) & 63;
  int b = gid >> 18;
  float p[8];
  #pragma unroll
  for (int k = 0; k < 8; ++k) {
    int row = (b * 8 + k) * 64 + i;
    p[k] = expf(sim3m[(size_t)row * cN + j] - rmax[row]) / rsum[row];
  }
  #pragma unroll
  for (int k2 = 0; k2 < 8; ++k2) {
    float t = 0.f;
    #pragma unroll
    for (int k = 0; k < 8; ++k) t += p[k] * w[k * 8 + k2];
    int row = (b * 8 + k2) * 64 + i;
    sim3m[(size_t)row * cN + j] = t;
  }
}

// ---------------------------------------------------------------------------
// K8: T3 partials: T3p[c][bh] = attn3f[bh][:, cchunk] @ v[bh][cchunk, :]
// ---------------------------------------------------------------------------
__global__ void __launch_bounds__(256) k_t3(const float* __restrict__ attn3f,
                                            const float* __restrict__ v,
                                            float* __restrict__ T3p) {
  __shared__ float As[64][65];
  __shared__ float Vs[64][68];
  int bh = blockIdx.x >> 2, chunk = blockIdx.x & 3;
  int tid = threadIdx.x;
  int ri = (tid >> 4) * 4, ci = (tid & 15) * 4;
  float acc[4][4] = {};
  for (int jt = chunk * 16; jt < chunk * 16 + 16; ++jt) {
    __syncthreads();
    const float* ap = attn3f + (size_t)bh * 64 * cN + jt * 64;
    for (int idx = tid; idx < 4096; idx += 256)
      As[idx >> 6][idx & 63] = ap[(size_t)(idx >> 6) * cN + (idx & 63)];
    const float* vp = v + ((size_t)bh * cN + jt * 64) * 64;
    for (int idx = tid; idx < 4096; idx += 256)
      Vs[idx >> 6][idx & 63] = vp[idx];
    __syncthreads();
    for (int j = 0; j < 64; ++j) {
      float a0 = As[ri][j], a1 = As[ri + 1][j], a2 = As[ri + 2][j], a3 = As[ri + 3][j];
      float b0 = Vs[j][ci], b1 = Vs[j][ci + 1], b2 = Vs[j][ci + 2], b3 = Vs[j][ci + 3];
      acc[0][0] += a0 * b0; acc[0][1] += a0 * b1; acc[0][2] += a0 * b2; acc[0][3] += a0 * b3;
      acc[1][0] += a1 * b0; acc[1][1] += a1 * b1; acc[1][2] += a1 * b2; acc[1][3] += a1 * b3;
      acc[2][0] += a2 * b0; acc[2][1] += a2 * b1; acc[2][2] += a2 * b2; acc[2][3] += a2 * b3;
      acc[3][0] += a3 * b0; acc[3][1] += a3 * b1; acc[3][2] += a3 * b2; acc[3][3] += a3 * b3;
    }
  }
  float* op = T3p + ((size_t)chunk * 64 + bh) * 4096;
  #pragma unroll
  for (int x = 0; x < 4; ++x)
    #pragma unroll
    for (int y = 0; y < 4; ++y)
      op[(ri + x) * 64 + ci + y] = acc[x][y];
}

// ---------------------------------------------------------------------------
// K9: T2[bh] = attn2m[bh] @ (sum of 4 T3 partials). Block per bh.
// ---------------------------------------------------------------------------
__global__ void __launch_bounds__(256) k_t2(const float* __restrict__ attn2m,
                                            const float* __restrict__ T3p,
                                            float* __restrict__ T2) {
  __shared__ float As[64][65];
  __shared__ float Bs[64][68];
  int bh = blockIdx.x, tid = threadIdx.x;
  const float* ap = attn2m + (size_t)bh * 4096;
  for (int idx = tid; idx < 4096; idx += 256) {
    As[idx >> 6][idx & 63] = ap[idx];
    float s = 0.f;
    #pragma unroll
    for (int c = 0; c < 4; ++c) s += T3p[((size_t)c * 64 + bh) * 4096 + idx];
    Bs[idx >> 6][idx & 63] = s;
  }
  __syncthreads();
  int ri = (tid >> 4) * 4, ci = (tid & 15) * 4;
  float acc[4][4] = {};
  for (int j = 0; j < 64; ++j) {
    float a0 = As[ri][j], a1 = As[ri + 1][j], a2 = As[ri + 2][j], a3 = As[ri + 3][j];
    float b0 = Bs[j][ci], b1 = Bs[j][ci + 1], b2 = Bs[j][ci + 2], b3 = Bs[j][ci + 3];
    acc[0][0] += a0 * b0; acc[0][1] += a0 * b1; acc[0][2] += a0 * b2; acc[0][3] += a0 * b3;
    acc[1][0] += a1 * b0; acc[1][1] += a1 * b1; acc[1][2] += a1 * b2; acc[1][3] += a1 * b3;
    acc[2][0] += a2 * b0; acc[2][1] += a2 * b1; acc[2][2] += a2 * b2; acc[2][3] += a2 * b3;
    acc[3][0] += a3 * b0; acc[3][1] += a3 * b1; acc[3][2] += a3 * b2; acc[3][3] += a3 * b3;
  }
  #pragma unroll
  for (int x = 0; x < 4; ++x)
    #pragma unroll
    for (int y = 0; y < 4; ++y)
      T2[(size_t)bh * 4096 + (ri + x) * 64 + ci + y] = acc[x][y];
}

// ---------------------------------------------------------------------------
// K10: conv residual -> d_out (R2 version, known-good: 154us, VALUBusy 79%,
// VGPR 92). u=8 variants all lost: no-bounds -> 64-cap spill; (256,2) ->
// 2 waves/SIMD latency-starved.
// ---------------------------------------------------------------------------
__global__ void __launch_bounds__(256) k_conv(const float* __restrict__ v,
                                              const float* __restrict__ cw,
                                              float* __restrict__ out) {
  __shared__ float wl[2112]; // [i][t][o] = i*264 + t*8 + o
  int tid = threadIdx.x;
  for (int idx = tid; idx < 2112; idx += 256) {
    int o = idx / 264, r = idx % 264, i = r / 33, t = r % 33;
    wl[i * 264 + t * 8 + o] = cw[idx];
  }
  __syncthreads();
  int d = tid & 63;
  int sub = tid >> 6;                        // 0..3
  int b = blockIdx.x >> 8;                   // 8 b
  int n0 = (blockIdx.x & 255) * 16 + sub * 4;
  float acc[8][4] = {};                      // [o][u]
  for (int i = 0; i < 8; ++i) {
    const float* vp = v + ((size_t)(b * 8 + i) * cN) * 64 + d;
    float win[36];
    #pragma unroll
    for (int t = 0; t < 36; ++t) {
      int nn = n0 - 16 + t;
      win[t] = (nn >= 0 && nn < cN) ? vp[(size_t)nn * 64] : 0.f;
    }
    #pragma unroll
    for (int t = 0; t < 33; ++t) {
      float4 w0 = *(const float4*)&wl[i * 264 + t * 8];
      float4 w1 = *(const float4*)&wl[i * 264 + t * 8 + 4];
      #pragma unroll
      for (int u = 0; u < 4; ++u) {
        float val = win[t + u];
        acc[0][u] += val * w0.x; acc[1][u] += val * w0.y;
        acc[2][u] += val * w0.z; acc[3][u] += val * w0.w;
        acc[4][u] += val * w1.x; acc[5][u] += val * w1.y;
        acc[6][u] += val * w1.z; acc[7][u] += val * w1.w;
      }
    }
  }
  #pragma unroll
  for (int o = 0; o < 8; ++o) {
    float* op = out + ((size_t)(b * 8 + o) * cN + n0) * 64 + d;
    #pragma unroll
    for (int u = 0; u < 4; ++u) op[(size_t)u * 64] = acc[o][u];
  }
}

// ---------------------------------------------------------------------------
// K11: fused sim1 chain (R8: 512 threads, 128-row block, 4i x 4j).
// R7 (256 thr, 64-row): spill fixed (VGPR 176, FETCH 74MB) but dur stayed
// 218us; Occupancy 11.5% = 1 wave/SIMD -> latency-bound (overhead 2.7x the
// 82us LDS floor vs R5's 1.7x at 2 waves/SIMD). Fix: double the block, not
// the tile: 512 thr, 128-row blocks, grid 256 = 1 block/CU, 8 waves/CU =
// 2 waves/SIMD. LDS: Q 2x128x68 + L 2x64x68 + w = 102.5KB -> 1 blk/CU.
// VGPR 176 x 2 waves = 352 <= 512 ok. Same LDS-instr floor (82us), R5-regime
// latency hiding, half the barriers per output row.
// Prediction: 218 -> ~140-160us; Occ ~23%; FETCH ~74MB (spill sentinel).
// ---------------------------------------------------------------------------
__device__ __forceinline__ void dot64_4x4(const float* __restrict__ A,   // row r0, pitch 68
                                          const float* __restrict__ Bm, int jb,
                                          float s[4][4]) {
  #pragma unroll
  for (int dc = 0; dc < 16; ++dc) {
    float4 kv0 = *(const float4*)&Bm[(dc * 4 + 0) * 68 + jb];
    float4 kv1 = *(const float4*)&Bm[(dc * 4 + 1) * 68 + jb];
    float4 kv2 = *(const float4*)&Bm[(dc * 4 + 2) * 68 + jb];
    float4 kv3 = *(const float4*)&Bm[(dc * 4 + 3) * 68 + jb];
    #pragma unroll
    for (int r = 0; r < 4; ++r) {
      float4 af = *(const float4*)&A[r * 68 + dc * 4];
      s[r][0] += af.x * kv0.x; s[r][1] += af.x * kv0.y; s[r][2] += af.x * kv0.z; s[r][3] += af.x * kv0.w;
      s[r][0] += af.y * kv1.x; s[r][1] += af.y * kv1.y; s[r][2] += af.y * kv1.z; s[r][3] += af.y * kv1.w;
      s[r][0] += af.z * kv2.x; s[r][1] += af.z * kv2.y; s[r][2] += af.z * kv2.z; s[r][3] += af.z * kv2.w;
      s[r][0] += af.w * kv3.x; s[r][1] += af.w * kv3.y; s[r][2] += af.w * kv3.z; s[r][3] += af.w * kv3.w;
    }
  }
}

// Stage a 128x64 tile (2048 float4) into LDS [128][68], 512 threads.
__device__ __forceinline__ void stage_q(float* __restrict__ dst,
                                        const float4* __restrict__ src, int tid) {
  int sr = tid >> 4, sc = (tid & 15) * 4;   // sr 0..31
  float4 a = src[tid];
  float4 b = src[tid + 512];
  float4 c = src[tid + 1024];
  float4 d = src[tid + 1536];
  *(float4*)&dst[sr * 68 + sc] = a;
  *(float4*)&dst[(32 + sr) * 68 + sc] = b;
  *(float4*)&dst[(64 + sr) * 68 + sc] = c;
  *(float4*)&dst[(96 + sr) * 68 + sc] = d;
}

// Stage a 64x64 tile (1024 float4) into LDS [64][68], 512 threads.
__device__ __forceinline__ void stage_l(float* __restrict__ dst,
                                        const float4* __restrict__ src, int tid) {
  int sr = tid >> 4, sc = (tid & 15) * 4;   // sr 0..31
  float4 a = src[tid];
  float4 b = src[tid + 512];
  *(float4*)&dst[sr * 68 + sc] = a;
  *(float4*)&dst[(32 + sr) * 68 + sc] = b;
}

__global__ void __launch_bounds__(512) k_final(const float* __restrict__ q,
                                               const float* __restrict__ klT,
                                               const float* __restrict__ T2,
                                               const float* __restrict__ Wsim1,
                                               const float* __restrict__ Wattn1,
                                               float* __restrict__ out) {
  // LDS: Q0|Q1 (128x68 each) + L0|L1 (64x68 each) + weights = 102.5 KB.
  // Phase1: Q=q-tile, L=klT-tile, parity h&1. Phase2: Q=P-tile, L=T2-tile.
  __shared__ float SB[2 * 128 * 68 + 2 * 64 * 68];
  __shared__ float ws1[64], wa1[64];
  constexpr int PITCH = 68, QBUF = 128 * 68, LBUF = 64 * 68;
  float* Q0 = SB;
  float* L0 = SB + 2 * QBUF;
  int b = blockIdx.x >> 5, i0 = (blockIdx.x & 31) * 128;
  int tid = threadIdx.x;
  if (tid < 64) { ws1[tid] = Wsim1[tid]; wa1[tid] = Wattn1[tid]; }
  int jb = (tid & 15) * 4, r0 = (tid >> 4) * 4;   // r0 0..124

  float sim[8][4][4] = {};   // [k][row][col] = 128 VGPR

  const float4* qb = (const float4*)(q + ((size_t)(b * 8) * cN + i0) * 64);
  const float4* kb = (const float4*)(klT + (size_t)(b * 8) * 4096);
  const float4* tb = (const float4*)(T2 + (size_t)(b * 8) * 4096);

  // prologue: h=0 tiles into buffer 0
  stage_q(Q0, qb, tid);
  stage_l(L0, kb, tid);
  __syncthreads();

  // ---- phase 1: h = 0..6 (stage h+1 at top, compute h, barrier) ----
  for (int h = 0; h < 7; ++h) {
    int p = h & 1, pn = p ^ 1;
    stage_q(Q0 + pn * QBUF, qb + (size_t)(h + 1) * 65536, tid);
    stage_l(L0 + pn * LBUF, kb + (size_t)(h + 1) * 1024, tid);
    float s[4][4] = {};
    dot64_4x4(Q0 + p * QBUF + r0 * PITCH, L0 + p * LBUF, jb, s);
    #pragma unroll
    for (int kq = 0; kq < 8; ++kq) {
      float wv = ws1[h * 8 + kq];
      #pragma unroll
      for (int r = 0; r < 4; ++r)
        #pragma unroll
        for (int c = 0; c < 4; ++c) sim[kq][r][c] += wv * s[r][c];
    }
    __syncthreads();
  }

  // ---- h = 7 (p = 1): stage T2[0] -> L0, compute, softmax+mix, P0 -> Q0 ----
  {
    stage_l(L0, tb, tid);
    float s[4][4] = {};
    dot64_4x4(Q0 + 1 * QBUF + r0 * PITCH, L0 + 1 * LBUF, jb, s);
    #pragma unroll
    for (int kq = 0; kq < 8; ++kq) {
      float wv = ws1[56 + kq];
      #pragma unroll
      for (int r = 0; r < 4; ++r)
        #pragma unroll
        for (int c = 0; c < 4; ++c) sim[kq][r][c] += wv * s[r][c];
    }
    // softmax over j=64 (16 lanes x 4 cols) for each of the 4 rows
    #pragma unroll
    for (int kq = 0; kq < 8; ++kq) {
      #pragma unroll
      for (int r = 0; r < 4; ++r) {
        float mx = fmaxf(fmaxf(sim[kq][r][0], sim[kq][r][1]),
                         fmaxf(sim[kq][r][2], sim[kq][r][3]));
        mx = fmaxf(mx, __shfl_xor(mx, 1)); mx = fmaxf(mx, __shfl_xor(mx, 2));
        mx = fmaxf(mx, __shfl_xor(mx, 4)); mx = fmaxf(mx, __shfl_xor(mx, 8));
        float sm = 0.f;
        #pragma unroll
        for (int c = 0; c < 4; ++c) {
          sim[kq][r][c] = expf(sim[kq][r][c] - mx);
          sm += sim[kq][r][c];
        }
        sm += __shfl_xor(sm, 1); sm += __shfl_xor(sm, 2);
        sm += __shfl_xor(sm, 4); sm += __shfl_xor(sm, 8);
        float inv = 1.0f / sm;
        #pragma unroll
        for (int c = 0; c < 4; ++c) sim[kq][r][c] *= inv;
      }
    }
    // Wattn1 mix in registers
    #pragma unroll
    for (int r = 0; r < 4; ++r)
      #pragma unroll
      for (int c = 0; c < 4; ++c) {
        float t[8];
        #pragma unroll
        for (int k2 = 0; k2 < 8; ++k2) {
          float a = 0.f;
          #pragma unroll
          for (int kk = 0; kk < 8; ++kk) a += sim[kk][r][c] * wa1[kk * 8 + k2];
          t[k2] = a;
        }
        #pragma unroll
        for (int k2 = 0; k2 < 8; ++k2) sim[k2][r][c] = t[k2];
      }
    // P[0] -> Q0
    #pragma unroll
    for (int r = 0; r < 4; ++r)
      *(float4*)&Q0[(r0 + r) * PITCH + jb] =
          make_float4(sim[0][r][0], sim[0][r][1], sim[0][r][2], sim[0][r][3]);
    __syncthreads();
  }

  // ---- phase 2: out[k2] += P[k2] @ T2[k2]; immediate global RMW per k2 ----
  #pragma unroll
  for (int k2 = 0; k2 < 8; ++k2) {
    int p = k2 & 1, pn = p ^ 1;
    if (k2 < 7) {
      stage_l(L0 + pn * LBUF, tb + (size_t)(k2 + 1) * 1024, tid);
      #pragma unroll
      for (int r = 0; r < 4; ++r)
        *(float4*)&Q0[pn * QBUF + (r0 + r) * PITCH + jb] =
            make_float4(sim[k2 + 1][r][0], sim[k2 + 1][r][1],
                        sim[k2 + 1][r][2], sim[k2 + 1][r][3]);
    }
    float o[4][4] = {};
    dot64_4x4(Q0 + p * QBUF + r0 * PITCH, L0 + p * LBUF, jb, o);
    #pragma unroll
    for (int r = 0; r < 4; ++r) {
      float* op = out + ((size_t)(b * 8 + k2) * cN + i0 + r0 + r) * 64 + jb;
      float4 e = *(float4*)op;
      e.x += o[r][0]; e.y += o[r][1]; e.z += o[r][2]; e.w += o[r][3];
      *(float4*)op = e;
    }
    if (k2 < 7) __syncthreads();
  }
}

// ---------------------------------------------------------------------------
extern "C" void kernel_launch(void* const* d_in, const int* in_sizes, int n_in,
                              void* d_out, int out_size, void* d_ws, size_t ws_size,
                              hipStream_t stream) {
  const float* q = (const float*)d_in[0];
  const float* k = (const float*)d_in[1];
  const float* v = (const float*)d_in[2];
  const float* Wsim1 = (const float*)d_in[3];
  const float* Wsim2 = (const float*)d_in[4];
  const float* Wsim3 = (const float*)d_in[5];
  const float* Wattn1 = (const float*)d_in[6];
  const float* Wattn2 = (const float*)d_in[7];
  const float* Wattn3 = (const float*)d_in[8];
  const float* cw = (const float*)d_in[9];
  float* out = (float*)d_out;
  float* ws = (float*)d_ws;

  float* ql       = ws + 0;
  float* kl       = ws + 262144;
  float* attn2    = ws + 524288;
  float* attn2inv = ws + 786432;
  float* attn2m   = ws + 1048576;
  float* T2       = ws + 1310720;
  float* rmax     = ws + 1572864;
  float* rsum     = ws + 1576960;
  unsigned int* scal = (unsigned int*)(ws + 1581056);
  float* T3p      = ws + 1581120;  // 4 * 64 * 4096 = 1,048,576 floats
  // d_out (exactly B*H*64*N floats) doubles as sim3m scratch; fully consumed
  // by k_t3 before k_conv overwrites d_out with the conv residual.
  float* sim3m = out;

  hipMemsetAsync(scal, 0, 8, stream);
  k_landmarks<<<dim3(4096), dim3(64), 0, stream>>>(q, k, ql, kl);
  k_sim2<<<dim3(64), dim3(256), 0, stream>>>(ql, kl, Wsim2, attn2, scal);
  // kl's last row-major reader is k_sim2; transpose it in place to [d][m]
  // so k_final can stage it linearly (conflict-free).
  k_klT<<<dim3(64), dim3(256), 0, stream>>>(kl);
  k_pinv<<<dim3(64), dim3(256), 0, stream>>>(attn2, attn2inv, scal);
  k_mix_heads64<<<dim3(64), dim3(256), 0, stream>>>(attn2inv, Wattn2, attn2m);
  k_sim3<<<dim3(1024), dim3(512), 0, stream>>>(ql, k, Wsim3, sim3m);
  k_stats3<<<dim3(4096), dim3(256), 0, stream>>>(sim3m, rmax, rsum);
  k_smx3<<<dim3(8192), dim3(256), 0, stream>>>(sim3m, rmax, rsum, Wattn3);
  k_t3<<<dim3(256), dim3(256), 0, stream>>>(sim3m, v, T3p);
  k_t2<<<dim3(64), dim3(256), 0, stream>>>(attn2m, T3p, T2);
  k_conv<<<dim3(2048), dim3(256), 0, stream>>>(v, cw, out);
  k_final<<<dim3(256), dim3(512), 0, stream>>>(q, kl, T2, Wsim1, Wattn1, out);
}

// Round 9
// 811.847 us; speedup vs baseline: 1.4187x; 1.0324x over previous
//
#include <hip/hip_runtime.h>
#include <cstddef>
#include <cstdint>

// Problem constants
constexpr int cB = 8, cH = 8, cN = 4096, cD = 64, cM = 64, cL = 64;

// ---------------------------------------------------------------------------
// K1: landmarks  q_l/k_l[bh][m][d] = mean over l=64 tokens
// (~at HBM floor: reads q+k = 1.07 GB once; irreducible)
// ---------------------------------------------------------------------------
__global__ void k_landmarks(const float* __restrict__ q, const float* __restrict__ k,
                            float* __restrict__ ql, float* __restrict__ kl) {
  int bm = blockIdx.x;          // BH*M = 4096
  int bh = bm >> 6, m = bm & 63;
  int d = threadIdx.x;          // 64
  size_t base = ((size_t)bh * cN + (size_t)m * cL) * cD + d;
  float sq = 0.f, sk = 0.f;
  for (int t = 0; t < cL; ++t) {
    sq += q[base + (size_t)t * cD];
    sk += k[base + (size_t)t * cD];
  }
  size_t ob = ((size_t)bh * cM + m) * cD + d;
  ql[ob] = sq * (1.0f / cL);
  kl[ob] = sk * (1.0f / cL);
}

// ---------------------------------------------------------------------------
// K2: sim2 = q_l k_l^T, mix heads (Wsim2), softmax rows, write attn2.
// Also atomicMax of global col-sum max (scal[0]) and row-sum max (scal[1]).
// ---------------------------------------------------------------------------
__global__ void __launch_bounds__(256) k_sim2(const float* __restrict__ ql,
                                              const float* __restrict__ kl,
                                              const float* __restrict__ Wsim2,
                                              float* __restrict__ attn2,
                                              unsigned int* __restrict__ scal) {
  __shared__ float qs[64][65];
  __shared__ float ks[64][65];
  __shared__ float acc[64 * 65];
  int b = blockIdx.x >> 3, kk = blockIdx.x & 7;
  int tid = threadIdx.x;
  for (int idx = tid; idx < 64 * 64; idx += 256)
    acc[(idx >> 6) * 65 + (idx & 63)] = 0.f;
  int ri = (tid >> 4) * 4, ci = (tid & 15) * 4;
  for (int h = 0; h < 8; ++h) {
    __syncthreads();
    const float* qg = ql + (size_t)(b * 8 + h) * 4096;
    const float* kg = kl + (size_t)(b * 8 + h) * 4096;
    for (int idx = tid; idx < 4096; idx += 256) {
      qs[idx >> 6][idx & 63] = qg[idx];
      ks[idx >> 6][idx & 63] = kg[idx];
    }
    __syncthreads();
    float w = Wsim2[h * 8 + kk];
    float s[4][4] = {};
    for (int d = 0; d < 64; ++d) {
      float a0 = qs[ri][d], a1 = qs[ri + 1][d], a2 = qs[ri + 2][d], a3 = qs[ri + 3][d];
      float b0 = ks[ci][d], b1 = ks[ci + 1][d], b2 = ks[ci + 2][d], b3 = ks[ci + 3][d];
      s[0][0] += a0 * b0; s[0][1] += a0 * b1; s[0][2] += a0 * b2; s[0][3] += a0 * b3;
      s[1][0] += a1 * b0; s[1][1] += a1 * b1; s[1][2] += a1 * b2; s[1][3] += a1 * b3;
      s[2][0] += a2 * b0; s[2][1] += a2 * b1; s[2][2] += a2 * b2; s[2][3] += a2 * b3;
      s[3][0] += a3 * b0; s[3][1] += a3 * b1; s[3][2] += a3 * b2; s[3][3] += a3 * b3;
    }
    #pragma unroll
    for (int x = 0; x < 4; ++x)
      #pragma unroll
      for (int y = 0; y < 4; ++y)
        acc[(ri + x) * 65 + ci + y] += w * s[x][y];
  }
  __syncthreads();
  if (tid < 64) {
    float mx = -1e30f;
    for (int j = 0; j < 64; ++j) mx = fmaxf(mx, acc[tid * 65 + j]);
    float s = 0.f;
    for (int j = 0; j < 64; ++j) {
      float e = expf(acc[tid * 65 + j] - mx);
      acc[tid * 65 + j] = e;
      s += e;
    }
    float inv = 1.0f / s;
    float rs = 0.f;
    for (int j = 0; j < 64; ++j) {
      float p = acc[tid * 65 + j] * inv;
      acc[tid * 65 + j] = p;
      rs += p;
    }
    atomicMax(scal + 1, __float_as_uint(rs));
  }
  __syncthreads();
  if (tid < 64) {
    float cs = 0.f;
    for (int i = 0; i < 64; ++i) cs += acc[i * 65 + tid];
    atomicMax(scal + 0, __float_as_uint(cs));
  }
  __syncthreads();
  float* op = attn2 + (size_t)(b * 8 + kk) * 4096;
  for (int idx = tid; idx < 4096; idx += 256)
    op[idx] = acc[(idx >> 6) * 65 + (idx & 63)];
}

// ---------------------------------------------------------------------------
// K2b: in-place transpose of kl [bh][m][d] -> [bh][d][m].
// ---------------------------------------------------------------------------
__global__ void k_klT(float* __restrict__ kl) {
  __shared__ float t[64 * 65];
  int bh = blockIdx.x, tid = threadIdx.x;
  float* p = kl + (size_t)bh * 4096;
  for (int idx = tid; idx < 4096; idx += 256)
    t[(idx >> 6) * 65 + (idx & 63)] = p[idx];
  __syncthreads();
  for (int idx = tid; idx < 4096; idx += 256)
    p[idx] = t[(idx & 63) * 65 + (idx >> 6)];
}

// ---------------------------------------------------------------------------
// K3: Moore-Penrose pinv, 6 Newton-Schulz iterations in LDS, per (b,k) block.
// ---------------------------------------------------------------------------
__device__ __forceinline__ void mm64(float* __restrict__ Dst, const float* S,
                                     float c0, float c1, const float* __restrict__ P,
                                     const float* __restrict__ Q, int tid) {
  int ri = (tid >> 4) * 4, ci = (tid & 15) * 4;
  float s[4][4] = {};
  for (int k = 0; k < 64; ++k) {
    float a0 = P[(ri + 0) * 65 + k], a1 = P[(ri + 1) * 65 + k];
    float a2 = P[(ri + 2) * 65 + k], a3 = P[(ri + 3) * 65 + k];
    float b0 = Q[k * 65 + ci + 0], b1 = Q[k * 65 + ci + 1];
    float b2 = Q[k * 65 + ci + 2], b3 = Q[k * 65 + ci + 3];
    s[0][0] += a0 * b0; s[0][1] += a0 * b1; s[0][2] += a0 * b2; s[0][3] += a0 * b3;
    s[1][0] += a1 * b0; s[1][1] += a1 * b1; s[1][2] += a1 * b2; s[1][3] += a1 * b3;
    s[2][0] += a2 * b0; s[2][1] += a2 * b1; s[2][2] += a2 * b2; s[2][3] += a2 * b3;
    s[3][0] += a3 * b0; s[3][1] += a3 * b1; s[3][2] += a3 * b2; s[3][3] += a3 * b3;
  }
  #pragma unroll
  for (int x = 0; x < 4; ++x)
    #pragma unroll
    for (int y = 0; y < 4; ++y) {
      float r = c1 * s[x][y];
      if (S) r += c0 * S[(ri + x) * 65 + ci + y];
      Dst[(ri + x) * 65 + ci + y] = r;
    }
}

__global__ void __launch_bounds__(256) k_pinv(const float* __restrict__ attn2,
                                              float* __restrict__ attn2inv,
                                              const unsigned int* __restrict__ scal) {
  __shared__ float bufs[5][64 * 65];
  float* X = bufs[0];
  float* Z = bufs[1];
  float* T1 = bufs[2];
  float* T2 = bufs[3];
  float* T3 = bufs[4];
  int tid = threadIdx.x;
  const float* xg = attn2 + (size_t)blockIdx.x * 4096;
  for (int idx = tid; idx < 4096; idx += 256)
    X[(idx >> 6) * 65 + (idx & 63)] = xg[idx];
  float denom = __uint_as_float(scal[0]) * __uint_as_float(scal[1]);
  float invd = 1.0f / denom;
  __syncthreads();
  for (int idx = tid; idx < 4096; idx += 256) {
    int i = idx >> 6, j = idx & 63;
    Z[i * 65 + j] = X[j * 65 + i] * invd;
  }
  __syncthreads();
  for (int it = 0; it < 6; ++it) {
    mm64(T1, nullptr, 0.f, 1.f, X, Z, tid);          __syncthreads();
    mm64(T2, T1, 7.f, -1.f, T1, T1, tid);            __syncthreads();
    mm64(T3, T1, 15.f, -1.f, T1, T2, tid);           __syncthreads();
    mm64(T2, Z, 13.f * 0.25f, -0.25f, Z, T3, tid);   __syncthreads();
    float* tmp = Z; Z = T2; T2 = tmp;
  }
  float* og = attn2inv + (size_t)blockIdx.x * 4096;
  for (int idx = tid; idx < 4096; idx += 256)
    og[idx] = Z[(idx >> 6) * 65 + (idx & 63)];
}

// ---------------------------------------------------------------------------
// K4: head-mix of 64x64 mats: out[b][k2] = sum_k in[b][k] * W[k][k2]
// ---------------------------------------------------------------------------
__global__ void k_mix_heads64(const float* __restrict__ in, const float* __restrict__ W,
                              float* __restrict__ out) {
  int b = blockIdx.x >> 3, k2 = blockIdx.x & 7;
  int tid = threadIdx.x;
  __shared__ float w[8];
  if (tid < 8) w[tid] = W[tid * 8 + k2];
  __syncthreads();
  const float* ib = in + (size_t)b * 8 * 4096;
  float* ob = out + ((size_t)b * 8 + k2) * 4096;
  for (int idx = tid; idx < 4096; idx += 256) {
    float s = 0.f;
    #pragma unroll
    for (int k = 0; k < 8; ++k) s += ib[(size_t)k * 4096 + idx] * w[k];
    ob[idx] = s;
  }
}

// ---------------------------------------------------------------------------
// K5: sim3m[b][k][i][j] = sum_h Wsim3[h][k]*(q_l[b,h,i,:].k[b,h,j,:])
// ---------------------------------------------------------------------------
__global__ void __launch_bounds__(512) k_sim3(const float* __restrict__ ql,
                                              const float* __restrict__ kg,
                                              const float* __restrict__ Wsim3,
                                              float* __restrict__ sim3m) {
  __shared__ float qls[64 * 65];   // [i][d] pitch 65
  __shared__ float ksT[64 * 36];   // [d][j] pitch 36 (16B-aligned float4 rows)
  __shared__ float w3[64];
  int b = blockIdx.x >> 7, jt = blockIdx.x & 127;
  int j0 = jt * 32, tid = threadIdx.x;
  if (tid < 64) w3[tid] = Wsim3[tid];
  int i = tid >> 3, jb = (tid & 7) * 4;
  float acc[8][4] = {};
  for (int h = 0; h < 8; ++h) {
    __syncthreads();
    const float* qg = ql + (size_t)(b * 8 + h) * 4096;
    for (int idx = tid; idx < 4096; idx += 512)
      qls[(idx >> 6) * 65 + (idx & 63)] = qg[idx];
    const float* kp = kg + ((size_t)(b * 8 + h) * cN + j0) * 64;
    for (int idx = tid; idx < 2048; idx += 512) {
      int j = idx >> 6, d = idx & 63;
      ksT[d * 36 + j] = kp[idx];
    }
    __syncthreads();
    float s[4] = {};
    for (int d = 0; d < 64; ++d) {
      float a = qls[i * 65 + d];
      float4 kv = *(const float4*)&ksT[d * 36 + jb];
      s[0] += a * kv.x; s[1] += a * kv.y; s[2] += a * kv.z; s[3] += a * kv.w;
    }
    #pragma unroll
    for (int k = 0; k < 8; ++k) {
      float w = w3[h * 8 + k];
      #pragma unroll
      for (int c = 0; c < 4; ++c) acc[k][c] += w * s[c];
    }
  }
  #pragma unroll
  for (int k = 0; k < 8; ++k) {
    float* op = sim3m + ((size_t)((b * 8 + k) * 64 + i)) * cN + j0 + jb;
    *(float4*)op = make_float4(acc[k][0], acc[k][1], acc[k][2], acc[k][3]);
  }
}

// ---------------------------------------------------------------------------
// K6+K7 fused (R9): k_smxt3 — row stats + softmax + Wattn3 mix, in place.
// Old: stats3 read 67MB; smx3 read 67 + write 67 (two passes over sim3m).
// New: one block per (b,i): stage all 8 k-rows (128KB LDS), stats in LDS,
// exp+mix, write back in place. One read + one write total. 512 thr =
// 2 waves/SIMD at 1 blk/CU (LDS-limited). Blocks own disjoint row sets ->
// in-place safe.
// ---------------------------------------------------------------------------
__global__ void __launch_bounds__(512) k_smxt3(float* __restrict__ sim3m,
                                               const float* __restrict__ Wattn3) {
  __shared__ float S[8][4096];
  __shared__ float w[64];
  __shared__ float red[8];
  int b = blockIdx.x >> 6, i = blockIdx.x & 63;
  int tid = threadIdx.x;
  if (tid < 64) w[tid] = Wattn3[tid];
  float m[8], inv[8];
  for (int k = 0; k < 8; ++k) {
    float* rp = sim3m + ((size_t)((b * 8 + k) * 64 + i)) * cN;
    float vv[8];
    float mx = -1e30f;
    #pragma unroll
    for (int t = 0; t < 8; ++t) {
      vv[t] = rp[tid + t * 512];
      S[k][tid + t * 512] = vv[t];
      mx = fmaxf(mx, vv[t]);
    }
    for (int off = 32; off > 0; off >>= 1) mx = fmaxf(mx, __shfl_down(mx, off));
    __syncthreads();                       // red reads from prev k done
    if ((tid & 63) == 0) red[tid >> 6] = mx;
    __syncthreads();
    mx = fmaxf(fmaxf(fmaxf(red[0], red[1]), fmaxf(red[2], red[3])),
               fmaxf(fmaxf(red[4], red[5]), fmaxf(red[6], red[7])));
    float s = 0.f;
    #pragma unroll
    for (int t = 0; t < 8; ++t) s += expf(vv[t] - mx);
    for (int off = 32; off > 0; off >>= 1) s += __shfl_down(s, off);
    __syncthreads();                       // red max reads done
    if ((tid & 63) == 0) red[tid >> 6] = s;
    __syncthreads();
    float st = red[0] + red[1] + red[2] + red[3] +
               red[4] + red[5] + red[6] + red[7];
    m[k] = mx;
    inv[k] = 1.0f / st;
  }
  __syncthreads();
  for (int j = tid; j < 4096; j += 512) {
    float p[8];
    #pragma unroll
    for (int k = 0; k < 8; ++k) p[k] = expf(S[k][j] - m[k]) * inv[k];
    #pragma unroll
    for (int k2 = 0; k2 < 8; ++k2) {
      float t = 0.f;
      #pragma unroll
      for (int k = 0; k < 8; ++k) t += p[k] * w[k * 8 + k2];
      sim3m[((size_t)((b * 8 + k2) * 64 + i)) * cN + j] = t;
    }
  }
}

// ---------------------------------------------------------------------------
// K8: T3 partials: T3p[c][bh] = attn3f[bh][:, cchunk] @ v[bh][cchunk, :]
// ---------------------------------------------------------------------------
__global__ void __launch_bounds__(256) k_t3(const float* __restrict__ attn3f,
                                            const float* __restrict__ v,
                                            float* __restrict__ T3p) {
  __shared__ float As[64][65];
  __shared__ float Vs[64][68];
  int bh = blockIdx.x >> 2, chunk = blockIdx.x & 3;
  int tid = threadIdx.x;
  int ri = (tid >> 4) * 4, ci = (tid & 15) * 4;
  float acc[4][4] = {};
  for (int jt = chunk * 16; jt < chunk * 16 + 16; ++jt) {
    __syncthreads();
    const float* ap = attn3f + (size_t)bh * 64 * cN + jt * 64;
    for (int idx = tid; idx < 4096; idx += 256)
      As[idx >> 6][idx & 63] = ap[(size_t)(idx >> 6) * cN + (idx & 63)];
    const float* vp = v + ((size_t)bh * cN + jt * 64) * 64;
    for (int idx = tid; idx < 4096; idx += 256)
      Vs[idx >> 6][idx & 63] = vp[idx];
    __syncthreads();
    for (int j = 0; j < 64; ++j) {
      float a0 = As[ri][j], a1 = As[ri + 1][j], a2 = As[ri + 2][j], a3 = As[ri + 3][j];
      float b0 = Vs[j][ci], b1 = Vs[j][ci + 1], b2 = Vs[j][ci + 2], b3 = Vs[j][ci + 3];
      acc[0][0] += a0 * b0; acc[0][1] += a0 * b1; acc[0][2] += a0 * b2; acc[0][3] += a0 * b3;
      acc[1][0] += a1 * b0; acc[1][1] += a1 * b1; acc[1][2] += a1 * b2; acc[1][3] += a1 * b3;
      acc[2][0] += a2 * b0; acc[2][1] += a2 * b1; acc[2][2] += a2 * b2; acc[2][3] += a2 * b3;
      acc[3][0] += a3 * b0; acc[3][1] += a3 * b1; acc[3][2] += a3 * b2; acc[3][3] += a3 * b3;
    }
  }
  float* op = T3p + ((size_t)chunk * 64 + bh) * 4096;
  #pragma unroll
  for (int x = 0; x < 4; ++x)
    #pragma unroll
    for (int y = 0; y < 4; ++y)
      op[(ri + x) * 64 + ci + y] = acc[x][y];
}

// ---------------------------------------------------------------------------
// K9: T2[bh] = attn2m[bh] @ (sum of 4 T3 partials). Block per bh.
// ---------------------------------------------------------------------------
__global__ void __launch_bounds__(256) k_t2(const float* __restrict__ attn2m,
                                            const float* __restrict__ T3p,
                                            float* __restrict__ T2) {
  __shared__ float As[64][65];
  __shared__ float Bs[64][68];
  int bh = blockIdx.x, tid = threadIdx.x;
  const float* ap = attn2m + (size_t)bh * 4096;
  for (int idx = tid; idx < 4096; idx += 256) {
    As[idx >> 6][idx & 63] = ap[idx];
    float s = 0.f;
    #pragma unroll
    for (int c = 0; c < 4; ++c) s += T3p[((size_t)c * 64 + bh) * 4096 + idx];
    Bs[idx >> 6][idx & 63] = s;
  }
  __syncthreads();
  int ri = (tid >> 4) * 4, ci = (tid & 15) * 4;
  float acc[4][4] = {};
  for (int j = 0; j < 64; ++j) {
    float a0 = As[ri][j], a1 = As[ri + 1][j], a2 = As[ri + 2][j], a3 = As[ri + 3][j];
    float b0 = Bs[j][ci], b1 = Bs[j][ci + 1], b2 = Bs[j][ci + 2], b3 = Bs[j][ci + 3];
    acc[0][0] += a0 * b0; acc[0][1] += a0 * b1; acc[0][2] += a0 * b2; acc[0][3] += a0 * b3;
    acc[1][0] += a1 * b0; acc[1][1] += a1 * b1; acc[1][2] += a1 * b2; acc[1][3] += a1 * b3;
    acc[2][0] += a2 * b0; acc[2][1] += a2 * b1; acc[2][2] += a2 * b2; acc[2][3] += a2 * b3;
    acc[3][0] += a3 * b0; acc[3][1] += a3 * b1; acc[3][2] += a3 * b2; acc[3][3] += a3 * b3;
  }
  #pragma unroll
  for (int x = 0; x < 4; ++x)
    #pragma unroll
    for (int y = 0; y < 4; ++y)
      T2[(size_t)bh * 4096 + (ri + x) * 64 + ci + y] = acc[x][y];
}

// ---------------------------------------------------------------------------
// K10: conv residual -> d_out (R9: u=8 tile, BARE launch_bounds).
// History: u=4 + bare(256) = 154us @ VGPR 92, VALUBusy 79% (2.2 inst/FMA,
// floor 56us). u=8 never ran unspilled: R3/R4 NO bounds -> 64-VGPR default
// cap -> spill; R5 (256,2) -> 128 pin + 2 waves/SIMD. This round: bare
// (256) + u=8 -> allocator free (~130-150 VGPR, ~3.5-4 waves/SIMD),
// 51 FMA/window-load vs 29. Sentinels: VGPR must be >100 (not 64);
// FETCH must stay ~98MB. Either fails -> revert to u=4 permanently.
// ---------------------------------------------------------------------------
__global__ void __launch_bounds__(256) k_conv(const float* __restrict__ v,
                                              const float* __restrict__ cw,
                                              float* __restrict__ out) {
  __shared__ float wl[2112]; // [i][t][o] = i*264 + t*8 + o
  int tid = threadIdx.x;
  for (int idx = tid; idx < 2112; idx += 256) {
    int o = idx / 264, r = idx % 264, i = r / 33, t = r % 33;
    wl[i * 264 + t * 8 + o] = cw[idx];
  }
  __syncthreads();
  int d = tid & 63;
  int sub = tid >> 6;                        // 0..3, uniform per wave
  int b = blockIdx.x >> 7;                   // 8 b
  int n0 = (blockIdx.x & 127) * 32 + sub * 8;
  int lo = n0 - 16;
  bool interior = (lo >= 0) && (lo + 39 < cN);   // wave-uniform branch
  float acc[8][8] = {};                      // [o][u]
  for (int i = 0; i < 8; ++i) {
    const float* vp = v + ((size_t)(b * 8 + i) * cN) * 64 + d;
    float win[40];
    if (interior) {
      #pragma unroll
      for (int t = 0; t < 40; ++t) win[t] = vp[(size_t)(lo + t) * 64];
    } else {
      #pragma unroll
      for (int t = 0; t < 40; ++t) {
        int nn = lo + t;
        win[t] = (nn >= 0 && nn < cN) ? vp[(size_t)nn * 64] : 0.f;
      }
    }
    #pragma unroll
    for (int t = 0; t < 33; ++t) {
      float4 w0 = *(const float4*)&wl[i * 264 + t * 8];
      float4 w1 = *(const float4*)&wl[i * 264 + t * 8 + 4];
      #pragma unroll
      for (int u = 0; u < 8; ++u) {
        float val = win[t + u];
        acc[0][u] += val * w0.x; acc[1][u] += val * w0.y;
        acc[2][u] += val * w0.z; acc[3][u] += val * w0.w;
        acc[4][u] += val * w1.x; acc[5][u] += val * w1.y;
        acc[6][u] += val * w1.z; acc[7][u] += val * w1.w;
      }
    }
  }
  #pragma unroll
  for (int o = 0; o < 8; ++o) {
    float* op = out + ((size_t)(b * 8 + o) * cN + n0) * 64 + d;
    #pragma unroll
    for (int u = 0; u < 8; ++u) op[(size_t)u * 64] = acc[o][u];
  }
}

// ---------------------------------------------------------------------------
// K11: fused sim1 chain (R8 version, kept: 512 thr, 128-row block, 4i x 4j,
// bare launch_bounds(512); VGPR 176 unspilled, ~2 waves/SIMD, dur <153us).
// ---------------------------------------------------------------------------
__device__ __forceinline__ void dot64_4x4(const float* __restrict__ A,   // row r0, pitch 68
                                          const float* __restrict__ Bm, int jb,
                                          float s[4][4]) {
  #pragma unroll
  for (int dc = 0; dc < 16; ++dc) {
    float4 kv0 = *(const float4*)&Bm[(dc * 4 + 0) * 68 + jb];
    float4 kv1 = *(const float4*)&Bm[(dc * 4 + 1) * 68 + jb];
    float4 kv2 = *(const float4*)&Bm[(dc * 4 + 2) * 68 + jb];
    float4 kv3 = *(const float4*)&Bm[(dc * 4 + 3) * 68 + jb];
    #pragma unroll
    for (int r = 0; r < 4; ++r) {
      float4 af = *(const float4*)&A[r * 68 + dc * 4];
      s[r][0] += af.x * kv0.x; s[r][1] += af.x * kv0.y; s[r][2] += af.x * kv0.z; s[r][3] += af.x * kv0.w;
      s[r][0] += af.y * kv1.x; s[r][1] += af.y * kv1.y; s[r][2] += af.y * kv1.z; s[r][3] += af.y * kv1.w;
      s[r][0] += af.z * kv2.x; s[r][1] += af.z * kv2.y; s[r][2] += af.z * kv2.z; s[r][3] += af.z * kv2.w;
      s[r][0] += af.w * kv3.x; s[r][1] += af.w * kv3.y; s[r][2] += af.w * kv3.z; s[r][3] += af.w * kv3.w;
    }
  }
}

// Stage a 128x64 tile (2048 float4) into LDS [128][68], 512 threads.
__device__ __forceinline__ void stage_q(float* __restrict__ dst,
                                        const float4* __restrict__ src, int tid) {
  int sr = tid >> 4, sc = (tid & 15) * 4;   // sr 0..31
  float4 a = src[tid];
  float4 b = src[tid + 512];
  float4 c = src[tid + 1024];
  float4 d = src[tid + 1536];
  *(float4*)&dst[sr * 68 + sc] = a;
  *(float4*)&dst[(32 + sr) * 68 + sc] = b;
  *(float4*)&dst[(64 + sr) * 68 + sc] = c;
  *(float4*)&dst[(96 + sr) * 68 + sc] = d;
}

// Stage a 64x64 tile (1024 float4) into LDS [64][68], 512 threads.
__device__ __forceinline__ void stage_l(float* __restrict__ dst,
                                        const float4* __restrict__ src, int tid) {
  int sr = tid >> 4, sc = (tid & 15) * 4;   // sr 0..31
  float4 a = src[tid];
  float4 b = src[tid + 512];
  *(float4*)&dst[sr * 68 + sc] = a;
  *(float4*)&dst[(32 + sr) * 68 + sc] = b;
}

__global__ void __launch_bounds__(512) k_final(const float* __restrict__ q,
                                               const float* __restrict__ klT,
                                               const float* __restrict__ T2,
                                               const float* __restrict__ Wsim1,
                                               const float* __restrict__ Wattn1,
                                               float* __restrict__ out) {
  // LDS: Q0|Q1 (128x68 each) + L0|L1 (64x68 each) + weights = 102.5 KB.
  __shared__ float SB[2 * 128 * 68 + 2 * 64 * 68];
  __shared__ float ws1[64], wa1[64];
  constexpr int PITCH = 68, QBUF = 128 * 68, LBUF = 64 * 68;
  float* Q0 = SB;
  float* L0 = SB + 2 * QBUF;
  int b = blockIdx.x >> 5, i0 = (blockIdx.x & 31) * 128;
  int tid = threadIdx.x;
  if (tid < 64) { ws1[tid] = Wsim1[tid]; wa1[tid] = Wattn1[tid]; }
  int jb = (tid & 15) * 4, r0 = (tid >> 4) * 4;   // r0 0..124

  float sim[8][4][4] = {};   // [k][row][col] = 128 VGPR

  const float4* qb = (const float4*)(q + ((size_t)(b * 8) * cN + i0) * 64);
  const float4* kb = (const float4*)(klT + (size_t)(b * 8) * 4096);
  const float4* tb = (const float4*)(T2 + (size_t)(b * 8) * 4096);

  // prologue: h=0 tiles into buffer 0
  stage_q(Q0, qb, tid);
  stage_l(L0, kb, tid);
  __syncthreads();

  // ---- phase 1: h = 0..6 (stage h+1 at top, compute h, barrier) ----
  for (int h = 0; h < 7; ++h) {
    int p = h & 1, pn = p ^ 1;
    stage_q(Q0 + pn * QBUF, qb + (size_t)(h + 1) * 65536, tid);
    stage_l(L0 + pn * LBUF, kb + (size_t)(h + 1) * 1024, tid);
    float s[4][4] = {};
    dot64_4x4(Q0 + p * QBUF + r0 * PITCH, L0 + p * LBUF, jb, s);
    #pragma unroll
    for (int kq = 0; kq < 8; ++kq) {
      float wv = ws1[h * 8 + kq];
      #pragma unroll
      for (int r = 0; r < 4; ++r)
        #pragma unroll
        for (int c = 0; c < 4; ++c) sim[kq][r][c] += wv * s[r][c];
    }
    __syncthreads();
  }

  // ---- h = 7 (p = 1): stage T2[0] -> L0, compute, softmax+mix, P0 -> Q0 ----
  {
    stage_l(L0, tb, tid);
    float s[4][4] = {};
    dot64_4x4(Q0 + 1 * QBUF + r0 * PITCH, L0 + 1 * LBUF, jb, s);
    #pragma unroll
    for (int kq = 0; kq < 8; ++kq) {
      float wv = ws1[56 + kq];
      #pragma unroll
      for (int r = 0; r < 4; ++r)
        #pragma unroll
        for (int c = 0; c < 4; ++c) sim[kq][r][c] += wv * s[r][c];
    }
    // softmax over j=64 (16 lanes x 4 cols) for each of the 4 rows
    #pragma unroll
    for (int kq = 0; kq < 8; ++kq) {
      #pragma unroll
      for (int r = 0; r < 4; ++r) {
        float mx = fmaxf(fmaxf(sim[kq][r][0], sim[kq][r][1]),
                         fmaxf(sim[kq][r][2], sim[kq][r][3]));
        mx = fmaxf(mx, __shfl_xor(mx, 1)); mx = fmaxf(mx, __shfl_xor(mx, 2));
        mx = fmaxf(mx, __shfl_xor(mx, 4)); mx = fmaxf(mx, __shfl_xor(mx, 8));
        float sm = 0.f;
        #pragma unroll
        for (int c = 0; c < 4; ++c) {
          sim[kq][r][c] = expf(sim[kq][r][c] - mx);
          sm += sim[kq][r][c];
        }
        sm += __shfl_xor(sm, 1); sm += __shfl_xor(sm, 2);
        sm += __shfl_xor(sm, 4); sm += __shfl_xor(sm, 8);
        float inv = 1.0f / sm;
        #pragma unroll
        for (int c = 0; c < 4; ++c) sim[kq][r][c] *= inv;
      }
    }
    // Wattn1 mix in registers
    #pragma unroll
    for (int r = 0; r < 4; ++r)
      #pragma unroll
      for (int c = 0; c < 4; ++c) {
        float t[8];
        #pragma unroll
        for (int k2 = 0; k2 < 8; ++k2) {
          float a = 0.f;
          #pragma unroll
          for (int kk = 0; kk < 8; ++kk) a += sim[kk][r][c] * wa1[kk * 8 + k2];
          t[k2] = a;
        }
        #pragma unroll
        for (int k2 = 0; k2 < 8; ++k2) sim[k2][r][c] = t[k2];
      }
    // P[0] -> Q0
    #pragma unroll
    for (int r = 0; r < 4; ++r)
      *(float4*)&Q0[(r0 + r) * PITCH + jb] =
          make_float4(sim[0][r][0], sim[0][r][1], sim[0][r][2], sim[0][r][3]);
    __syncthreads();
  }

  // ---- phase 2: out[k2] += P[k2] @ T2[k2]; immediate global RMW per k2 ----
  #pragma unroll
  for (int k2 = 0; k2 < 8; ++k2) {
    int p = k2 & 1, pn = p ^ 1;
    if (k2 < 7) {
      stage_l(L0 + pn * LBUF, tb + (size_t)(k2 + 1) * 1024, tid);
      #pragma unroll
      for (int r = 0; r < 4; ++r)
        *(float4*)&Q0[pn * QBUF + (r0 + r) * PITCH + jb] =
            make_float4(sim[k2 + 1][r][0], sim[k2 + 1][r][1],
                        sim[k2 + 1][r][2], sim[k2 + 1][r][3]);
    }
    float o[4][4] = {};
    dot64_4x4(Q0 + p * QBUF + r0 * PITCH, L0 + p * LBUF, jb, o);
    #pragma unroll
    for (int r = 0; r < 4; ++r) {
      float* op = out + ((size_t)(b * 8 + k2) * cN + i0 + r0 + r) * 64 + jb;
      float4 e = *(float4*)op;
      e.x += o[r][0]; e.y += o[r][1]; e.z += o[r][2]; e.w += o[r][3];
      *(float4*)op = e;
    }
    if (k2 < 7) __syncthreads();
  }
}

// ---------------------------------------------------------------------------
extern "C" void kernel_launch(void* const* d_in, const int* in_sizes, int n_in,
                              void* d_out, int out_size, void* d_ws, size_t ws_size,
                              hipStream_t stream) {
  const float* q = (const float*)d_in[0];
  const float* k = (const float*)d_in[1];
  const float* v = (const float*)d_in[2];
  const float* Wsim1 = (const float*)d_in[3];
  const float* Wsim2 = (const float*)d_in[4];
  const float* Wsim3 = (const float*)d_in[5];
  const float* Wattn1 = (const float*)d_in[6];
  const float* Wattn2 = (const float*)d_in[7];
  const float* Wattn3 = (const float*)d_in[8];
  const float* cw = (const float*)d_in[9];
  float* out = (float*)d_out;
  float* ws = (float*)d_ws;

  float* ql       = ws + 0;
  float* kl       = ws + 262144;
  float* attn2    = ws + 524288;
  float* attn2inv = ws + 786432;
  float* attn2m   = ws + 1048576;
  float* T2       = ws + 1310720;
  unsigned int* scal = (unsigned int*)(ws + 1581056);
  float* T3p      = ws + 1581120;  // 4 * 64 * 4096 = 1,048,576 floats
  // d_out (exactly B*H*64*N floats) doubles as sim3m scratch; fully consumed
  // by k_t3 before k_conv overwrites d_out with the conv residual.
  float* sim3m = out;

  hipMemsetAsync(scal, 0, 8, stream);
  k_landmarks<<<dim3(4096), dim3(64), 0, stream>>>(q, k, ql, kl);
  k_sim2<<<dim3(64), dim3(256), 0, stream>>>(ql, kl, Wsim2, attn2, scal);
  // kl's last row-major reader is k_sim2; transpose it in place to [d][m]
  // so k_final can stage it linearly (conflict-free).
  k_klT<<<dim3(64), dim3(256), 0, stream>>>(kl);
  k_pinv<<<dim3(64), dim3(256), 0, stream>>>(attn2, attn2inv, scal);
  k_mix_heads64<<<dim3(64), dim3(256), 0, stream>>>(attn2inv, Wattn2, attn2m);
  k_sim3<<<dim3(1024), dim3(512), 0, stream>>>(ql, k, Wsim3, sim3m);
  // fused row-stats + softmax + Wattn3 mix, in place on sim3m
  k_smxt3<<<dim3(512), dim3(512), 0, stream>>>(sim3m, Wattn3);
  k_t3<<<dim3(256), dim3(256), 0, stream>>>(sim3m, v, T3p);
  k_t2<<<dim3(64), dim3(256), 0, stream>>>(attn2m, T3p, T2);
  k_conv<<<dim3(1024), dim3(256), 0, stream>>>(v, cw, out);
  k_final<<<dim3(256), dim3(512), 0, stream>>>(q, kl, T2, Wsim1, Wattn1, out);
}

// Round 10
// 805.440 us; speedup vs baseline: 1.4300x; 1.0080x over previous
//
#include <hip/hip_runtime.h>
#include <cstddef>
#include <cstdint>

// Problem constants
constexpr int cB = 8, cH = 8, cN = 4096, cD = 64, cM = 64, cL = 64;

// ---------------------------------------------------------------------------
// K1: landmarks  q_l/k_l[bh][m][d] = mean over l=64 tokens
// ---------------------------------------------------------------------------
__global__ void k_landmarks(const float* __restrict__ q, const float* __restrict__ k,
                            float* __restrict__ ql, float* __restrict__ kl) {
  int bm = blockIdx.x;          // BH*M = 4096
  int bh = bm >> 6, m = bm & 63;
  int d = threadIdx.x;          // 64
  size_t base = ((size_t)bh * cN + (size_t)m * cL) * cD + d;
  float sq = 0.f, sk = 0.f;
  for (int t = 0; t < cL; ++t) {
    sq += q[base + (size_t)t * cD];
    sk += k[base + (size_t)t * cD];
  }
  size_t ob = ((size_t)bh * cM + m) * cD + d;
  ql[ob] = sq * (1.0f / cL);
  kl[ob] = sk * (1.0f / cL);
}

// ---------------------------------------------------------------------------
// K2: sim2 = q_l k_l^T, mix heads (Wsim2), softmax rows, write attn2 + scal.
// R10: ALSO writes klT[b*8+kk] (transposed kl head) from its staged ks tile
// when h==kk — replaces the separate k_klT kernel. Each (b,kk) block covers
// head kk of batch b exactly once.
// ---------------------------------------------------------------------------
__global__ void __launch_bounds__(256) k_sim2(const float* __restrict__ ql,
                                              const float* __restrict__ kl,
                                              const float* __restrict__ Wsim2,
                                              float* __restrict__ attn2,
                                              unsigned int* __restrict__ scal,
                                              float* __restrict__ klT) {
  __shared__ float qs[64][65];
  __shared__ float ks[64][65];
  __shared__ float acc[64 * 65];
  int b = blockIdx.x >> 3, kk = blockIdx.x & 7;
  int tid = threadIdx.x;
  for (int idx = tid; idx < 64 * 64; idx += 256)
    acc[(idx >> 6) * 65 + (idx & 63)] = 0.f;
  int ri = (tid >> 4) * 4, ci = (tid & 15) * 4;
  for (int h = 0; h < 8; ++h) {
    __syncthreads();
    const float* qg = ql + (size_t)(b * 8 + h) * 4096;
    const float* kg = kl + (size_t)(b * 8 + h) * 4096;
    for (int idx = tid; idx < 4096; idx += 256) {
      qs[idx >> 6][idx & 63] = qg[idx];
      ks[idx >> 6][idx & 63] = kg[idx];
    }
    __syncthreads();
    if (h == kk) {
      // write klT[d][m] = kl[m][d], coalesced over m; ks pitch 65 -> no conflicts
      float* op = klT + (size_t)(b * 8 + kk) * 4096;
      for (int idx = tid; idx < 4096; idx += 256)
        op[idx] = ks[idx & 63][idx >> 6];
    }
    float w = Wsim2[h * 8 + kk];
    float s[4][4] = {};
    for (int d = 0; d < 64; ++d) {
      float a0 = qs[ri][d], a1 = qs[ri + 1][d], a2 = qs[ri + 2][d], a3 = qs[ri + 3][d];
      float b0 = ks[ci][d], b1 = ks[ci + 1][d], b2 = ks[ci + 2][d], b3 = ks[ci + 3][d];
      s[0][0] += a0 * b0; s[0][1] += a0 * b1; s[0][2] += a0 * b2; s[0][3] += a0 * b3;
      s[1][0] += a1 * b0; s[1][1] += a1 * b1; s[1][2] += a1 * b2; s[1][3] += a1 * b3;
      s[2][0] += a2 * b0; s[2][1] += a2 * b1; s[2][2] += a2 * b2; s[2][3] += a2 * b3;
      s[3][0] += a3 * b0; s[3][1] += a3 * b1; s[3][2] += a3 * b2; s[3][3] += a3 * b3;
    }
    #pragma unroll
    for (int x = 0; x < 4; ++x)
      #pragma unroll
      for (int y = 0; y < 4; ++y)
        acc[(ri + x) * 65 + ci + y] += w * s[x][y];
  }
  __syncthreads();
  if (tid < 64) {
    float mx = -1e30f;
    for (int j = 0; j < 64; ++j) mx = fmaxf(mx, acc[tid * 65 + j]);
    float s = 0.f;
    for (int j = 0; j < 64; ++j) {
      float e = expf(acc[tid * 65 + j] - mx);
      acc[tid * 65 + j] = e;
      s += e;
    }
    float inv = 1.0f / s;
    float rs = 0.f;
    for (int j = 0; j < 64; ++j) {
      float p = acc[tid * 65 + j] * inv;
      acc[tid * 65 + j] = p;
      rs += p;
    }
    atomicMax(scal + 1, __float_as_uint(rs));
  }
  __syncthreads();
  if (tid < 64) {
    float cs = 0.f;
    for (int i = 0; i < 64; ++i) cs += acc[i * 65 + tid];
    atomicMax(scal + 0, __float_as_uint(cs));
  }
  __syncthreads();
  float* op = attn2 + (size_t)(b * 8 + kk) * 4096;
  for (int idx = tid; idx < 4096; idx += 256)
    op[idx] = acc[(idx >> 6) * 65 + (idx & 63)];
}

// ---------------------------------------------------------------------------
// K3: Moore-Penrose pinv, 6 Newton-Schulz iterations in LDS, per (b,k) block.
// ---------------------------------------------------------------------------
__device__ __forceinline__ void mm64(float* __restrict__ Dst, const float* S,
                                     float c0, float c1, const float* __restrict__ P,
                                     const float* __restrict__ Q, int tid) {
  int ri = (tid >> 4) * 4, ci = (tid & 15) * 4;
  float s[4][4] = {};
  for (int k = 0; k < 64; ++k) {
    float a0 = P[(ri + 0) * 65 + k], a1 = P[(ri + 1) * 65 + k];
    float a2 = P[(ri + 2) * 65 + k], a3 = P[(ri + 3) * 65 + k];
    float b0 = Q[k * 65 + ci + 0], b1 = Q[k * 65 + ci + 1];
    float b2 = Q[k * 65 + ci + 2], b3 = Q[k * 65 + ci + 3];
    s[0][0] += a0 * b0; s[0][1] += a0 * b1; s[0][2] += a0 * b2; s[0][3] += a0 * b3;
    s[1][0] += a1 * b0; s[1][1] += a1 * b1; s[1][2] += a1 * b2; s[1][3] += a1 * b3;
    s[2][0] += a2 * b0; s[2][1] += a2 * b1; s[2][2] += a2 * b2; s[2][3] += a2 * b3;
    s[3][0] += a3 * b0; s[3][1] += a3 * b1; s[3][2] += a3 * b2; s[3][3] += a3 * b3;
  }
  #pragma unroll
  for (int x = 0; x < 4; ++x)
    #pragma unroll
    for (int y = 0; y < 4; ++y) {
      float r = c1 * s[x][y];
      if (S) r += c0 * S[(ri + x) * 65 + ci + y];
      Dst[(ri + x) * 65 + ci + y] = r;
    }
}

__global__ void __launch_bounds__(256) k_pinv(const float* __restrict__ attn2,
                                              float* __restrict__ attn2inv,
                                              const unsigned int* __restrict__ scal) {
  __shared__ float bufs[5][64 * 65];
  float* X = bufs[0];
  float* Z = bufs[1];
  float* T1 = bufs[2];
  float* T2 = bufs[3];
  float* T3 = bufs[4];
  int tid = threadIdx.x;
  const float* xg = attn2 + (size_t)blockIdx.x * 4096;
  for (int idx = tid; idx < 4096; idx += 256)
    X[(idx >> 6) * 65 + (idx & 63)] = xg[idx];
  float denom = __uint_as_float(scal[0]) * __uint_as_float(scal[1]);
  float invd = 1.0f / denom;
  __syncthreads();
  for (int idx = tid; idx < 4096; idx += 256) {
    int i = idx >> 6, j = idx & 63;
    Z[i * 65 + j] = X[j * 65 + i] * invd;
  }
  __syncthreads();
  for (int it = 0; it < 6; ++it) {
    mm64(T1, nullptr, 0.f, 1.f, X, Z, tid);          __syncthreads();
    mm64(T2, T1, 7.f, -1.f, T1, T1, tid);            __syncthreads();
    mm64(T3, T1, 15.f, -1.f, T1, T2, tid);           __syncthreads();
    mm64(T2, Z, 13.f * 0.25f, -0.25f, Z, T3, tid);   __syncthreads();
    float* tmp = Z; Z = T2; T2 = tmp;
  }
  float* og = attn2inv + (size_t)blockIdx.x * 4096;
  for (int idx = tid; idx < 4096; idx += 256)
    og[idx] = Z[(idx >> 6) * 65 + (idx & 63)];
}

// ---------------------------------------------------------------------------
// K5: sim3m[b][k][i][j] = sum_h Wsim3[h][k]*(q_l[b,h,i,:].k[b,h,j,:])
// ---------------------------------------------------------------------------
__global__ void __launch_bounds__(512) k_sim3(const float* __restrict__ ql,
                                              const float* __restrict__ kg,
                                              const float* __restrict__ Wsim3,
                                              float* __restrict__ sim3m) {
  __shared__ float qls[64 * 65];   // [i][d] pitch 65
  __shared__ float ksT[64 * 36];   // [d][j] pitch 36 (16B-aligned float4 rows)
  __shared__ float w3[64];
  int b = blockIdx.x >> 7, jt = blockIdx.x & 127;
  int j0 = jt * 32, tid = threadIdx.x;
  if (tid < 64) w3[tid] = Wsim3[tid];
  int i = tid >> 3, jb = (tid & 7) * 4;
  float acc[8][4] = {};
  for (int h = 0; h < 8; ++h) {
    __syncthreads();
    const float* qg = ql + (size_t)(b * 8 + h) * 4096;
    for (int idx = tid; idx < 4096; idx += 512)
      qls[(idx >> 6) * 65 + (idx & 63)] = qg[idx];
    const float* kp = kg + ((size_t)(b * 8 + h) * cN + j0) * 64;
    for (int idx = tid; idx < 2048; idx += 512) {
      int j = idx >> 6, d = idx & 63;
      ksT[d * 36 + j] = kp[idx];
    }
    __syncthreads();
    float s[4] = {};
    for (int d = 0; d < 64; ++d) {
      float a = qls[i * 65 + d];
      float4 kv = *(const float4*)&ksT[d * 36 + jb];
      s[0] += a * kv.x; s[1] += a * kv.y; s[2] += a * kv.z; s[3] += a * kv.w;
    }
    #pragma unroll
    for (int k = 0; k < 8; ++k) {
      float w = w3[h * 8 + k];
      #pragma unroll
      for (int c = 0; c < 4; ++c) acc[k][c] += w * s[c];
    }
  }
  #pragma unroll
  for (int k = 0; k < 8; ++k) {
    float* op = sim3m + ((size_t)((b * 8 + k) * 64 + i)) * cN + j0 + jb;
    *(float4*)op = make_float4(acc[k][0], acc[k][1], acc[k][2], acc[k][3]);
  }
}

// ---------------------------------------------------------------------------
// K6+K7 fused: k_smxt3 — row stats + softmax + Wattn3 mix, in place.
// ---------------------------------------------------------------------------
__global__ void __launch_bounds__(512) k_smxt3(float* __restrict__ sim3m,
                                               const float* __restrict__ Wattn3) {
  __shared__ float S[8][4096];
  __shared__ float w[64];
  __shared__ float red[8];
  int b = blockIdx.x >> 6, i = blockIdx.x & 63;
  int tid = threadIdx.x;
  if (tid < 64) w[tid] = Wattn3[tid];
  float m[8], inv[8];
  for (int k = 0; k < 8; ++k) {
    float* rp = sim3m + ((size_t)((b * 8 + k) * 64 + i)) * cN;
    float vv[8];
    float mx = -1e30f;
    #pragma unroll
    for (int t = 0; t < 8; ++t) {
      vv[t] = rp[tid + t * 512];
      S[k][tid + t * 512] = vv[t];
      mx = fmaxf(mx, vv[t]);
    }
    for (int off = 32; off > 0; off >>= 1) mx = fmaxf(mx, __shfl_down(mx, off));
    __syncthreads();                       // red reads from prev k done
    if ((tid & 63) == 0) red[tid >> 6] = mx;
    __syncthreads();
    mx = fmaxf(fmaxf(fmaxf(red[0], red[1]), fmaxf(red[2], red[3])),
               fmaxf(fmaxf(red[4], red[5]), fmaxf(red[6], red[7])));
    float s = 0.f;
    #pragma unroll
    for (int t = 0; t < 8; ++t) s += expf(vv[t] - mx);
    for (int off = 32; off > 0; off >>= 1) s += __shfl_down(s, off);
    __syncthreads();                       // red max reads done
    if ((tid & 63) == 0) red[tid >> 6] = s;
    __syncthreads();
    float st = red[0] + red[1] + red[2] + red[3] +
               red[4] + red[5] + red[6] + red[7];
    m[k] = mx;
    inv[k] = 1.0f / st;
  }
  __syncthreads();
  for (int j = tid; j < 4096; j += 512) {
    float p[8];
    #pragma unroll
    for (int k = 0; k < 8; ++k) p[k] = expf(S[k][j] - m[k]) * inv[k];
    #pragma unroll
    for (int k2 = 0; k2 < 8; ++k2) {
      float t = 0.f;
      #pragma unroll
      for (int k = 0; k < 8; ++k) t += p[k] * w[k * 8 + k2];
      sim3m[((size_t)((b * 8 + k2) * 64 + i)) * cN + j] = t;
    }
  }
}

// ---------------------------------------------------------------------------
// K8: T3 partials: T3p[c][bh] = attn3f[bh][:, cchunk] @ v[bh][cchunk, :]
// ---------------------------------------------------------------------------
__global__ void __launch_bounds__(256) k_t3(const float* __restrict__ attn3f,
                                            const float* __restrict__ v,
                                            float* __restrict__ T3p) {
  __shared__ float As[64][65];
  __shared__ float Vs[64][68];
  int bh = blockIdx.x >> 2, chunk = blockIdx.x & 3;
  int tid = threadIdx.x;
  int ri = (tid >> 4) * 4, ci = (tid & 15) * 4;
  float acc[4][4] = {};
  for (int jt = chunk * 16; jt < chunk * 16 + 16; ++jt) {
    __syncthreads();
    const float* ap = attn3f + (size_t)bh * 64 * cN + jt * 64;
    for (int idx = tid; idx < 4096; idx += 256)
      As[idx >> 6][idx & 63] = ap[(size_t)(idx >> 6) * cN + (idx & 63)];
    const float* vp = v + ((size_t)bh * cN + jt * 64) * 64;
    for (int idx = tid; idx < 4096; idx += 256)
      Vs[idx >> 6][idx & 63] = vp[idx];
    __syncthreads();
    for (int j = 0; j < 64; ++j) {
      float a0 = As[ri][j], a1 = As[ri + 1][j], a2 = As[ri + 2][j], a3 = As[ri + 3][j];
      float b0 = Vs[j][ci], b1 = Vs[j][ci + 1], b2 = Vs[j][ci + 2], b3 = Vs[j][ci + 3];
      acc[0][0] += a0 * b0; acc[0][1] += a0 * b1; acc[0][2] += a0 * b2; acc[0][3] += a0 * b3;
      acc[1][0] += a1 * b0; acc[1][1] += a1 * b1; acc[1][2] += a1 * b2; acc[1][3] += a1 * b3;
      acc[2][0] += a2 * b0; acc[2][1] += a2 * b1; acc[2][2] += a2 * b2; acc[2][3] += a2 * b3;
      acc[3][0] += a3 * b0; acc[3][1] += a3 * b1; acc[3][2] += a3 * b2; acc[3][3] += a3 * b3;
    }
  }
  float* op = T3p + ((size_t)chunk * 64 + bh) * 4096;
  #pragma unroll
  for (int x = 0; x < 4; ++x)
    #pragma unroll
    for (int y = 0; y < 4; ++y)
      op[(ri + x) * 64 + ci + y] = acc[x][y];
}

// ---------------------------------------------------------------------------
// K9 (R10): T2[bh] = attn2m[bh] @ (sum of 4 T3 partials), where attn2m is
// computed ON THE FLY from attn2inv + Wattn2 during As staging (attn2m was
// consumed only here — k_mix_heads64 kernel deleted). 8x As staging reads
// hit L2 (attn2inv = 1MB, just written by k_pinv).
// ---------------------------------------------------------------------------
__global__ void __launch_bounds__(256) k_t2(const float* __restrict__ attn2inv,
                                            const float* __restrict__ Wattn2,
                                            const float* __restrict__ T3p,
                                            float* __restrict__ T2) {
  __shared__ float As[64][65];
  __shared__ float Bs[64][68];
  __shared__ float w2[8];
  int bh = blockIdx.x, tid = threadIdx.x;
  int b = bh >> 3, h = bh & 7;
  if (tid < 8) w2[tid] = Wattn2[tid * 8 + h];
  __syncthreads();
  const float* ib = attn2inv + (size_t)b * 8 * 4096;
  for (int idx = tid; idx < 4096; idx += 256) {
    float s = 0.f;
    #pragma unroll
    for (int k = 0; k < 8; ++k) s += ib[(size_t)k * 4096 + idx] * w2[k];
    As[idx >> 6][idx & 63] = s;
    float t = 0.f;
    #pragma unroll
    for (int c = 0; c < 4; ++c) t += T3p[((size_t)c * 64 + bh) * 4096 + idx];
    Bs[idx >> 6][idx & 63] = t;
  }
  __syncthreads();
  int ri = (tid >> 4) * 4, ci = (tid & 15) * 4;
  float acc[4][4] = {};
  for (int j = 0; j < 64; ++j) {
    float a0 = As[ri][j], a1 = As[ri + 1][j], a2 = As[ri + 2][j], a3 = As[ri + 3][j];
    float b0 = Bs[j][ci], b1 = Bs[j][ci + 1], b2 = Bs[j][ci + 2], b3 = Bs[j][ci + 3];
    acc[0][0] += a0 * b0; acc[0][1] += a0 * b1; acc[0][2] += a0 * b2; acc[0][3] += a0 * b3;
    acc[1][0] += a1 * b0; acc[1][1] += a1 * b1; acc[1][2] += a1 * b2; acc[1][3] += a1 * b3;
    acc[2][0] += a2 * b0; acc[2][1] += a2 * b1; acc[2][2] += a2 * b2; acc[2][3] += a2 * b3;
    acc[3][0] += a3 * b0; acc[3][1] += a3 * b1; acc[3][2] += a3 * b2; acc[3][3] += a3 * b3;
  }
  #pragma unroll
  for (int x = 0; x < 4; ++x)
    #pragma unroll
    for (int y = 0; y < 4; ++y)
      T2[(size_t)bh * 4096 + (ri + x) * 64 + ci + y] = acc[x][y];
}

// ---------------------------------------------------------------------------
// K10: conv residual -> d_out (R9 version kept: u=8 tile, bare
// launch_bounds(256); ran unspilled, <139us).
// ---------------------------------------------------------------------------
__global__ void __launch_bounds__(256) k_conv(const float* __restrict__ v,
                                              const float* __restrict__ cw,
                                              float* __restrict__ out) {
  __shared__ float wl[2112]; // [i][t][o] = i*264 + t*8 + o
  int tid = threadIdx.x;
  for (int idx = tid; idx < 2112; idx += 256) {
    int o = idx / 264, r = idx % 264, i = r / 33, t = r % 33;
    wl[i * 264 + t * 8 + o] = cw[idx];
  }
  __syncthreads();
  int d = tid & 63;
  int sub = tid >> 6;                        // 0..3, uniform per wave
  int b = blockIdx.x >> 7;                   // 8 b
  int n0 = (blockIdx.x & 127) * 32 + sub * 8;
  int lo = n0 - 16;
  bool interior = (lo >= 0) && (lo + 39 < cN);   // wave-uniform branch
  float acc[8][8] = {};                      // [o][u]
  for (int i = 0; i < 8; ++i) {
    const float* vp = v + ((size_t)(b * 8 + i) * cN) * 64 + d;
    float win[40];
    if (interior) {
      #pragma unroll
      for (int t = 0; t < 40; ++t) win[t] = vp[(size_t)(lo + t) * 64];
    } else {
      #pragma unroll
      for (int t = 0; t < 40; ++t) {
        int nn = lo + t;
        win[t] = (nn >= 0 && nn < cN) ? vp[(size_t)nn * 64] : 0.f;
      }
    }
    #pragma unroll
    for (int t = 0; t < 33; ++t) {
      float4 w0 = *(const float4*)&wl[i * 264 + t * 8];
      float4 w1 = *(const float4*)&wl[i * 264 + t * 8 + 4];
      #pragma unroll
      for (int u = 0; u < 8; ++u) {
        float val = win[t + u];
        acc[0][u] += val * w0.x; acc[1][u] += val * w0.y;
        acc[2][u] += val * w0.z; acc[3][u] += val * w0.w;
        acc[4][u] += val * w1.x; acc[5][u] += val * w1.y;
        acc[6][u] += val * w1.z; acc[7][u] += val * w1.w;
      }
    }
  }
  #pragma unroll
  for (int o = 0; o < 8; ++o) {
    float* op = out + ((size_t)(b * 8 + o) * cN + n0) * 64 + d;
    #pragma unroll
    for (int u = 0; u < 8; ++u) op[(size_t)u * 64] = acc[o][u];
  }
}

// ---------------------------------------------------------------------------
// K11: fused sim1 chain (R8/R9 version kept: 512 thr, 128-row block, 4i x 4j,
// bare launch_bounds(512); 139us, VGPR 128 w/ mild one-time spill ~10us).
// ---------------------------------------------------------------------------
__device__ __forceinline__ void dot64_4x4(const float* __restrict__ A,   // row r0, pitch 68
                                          const float* __restrict__ Bm, int jb,
                                          float s[4][4]) {
  #pragma unroll
  for (int dc = 0; dc < 16; ++dc) {
    float4 kv0 = *(const float4*)&Bm[(dc * 4 + 0) * 68 + jb];
    float4 kv1 = *(const float4*)&Bm[(dc * 4 + 1) * 68 + jb];
    float4 kv2 = *(const float4*)&Bm[(dc * 4 + 2) * 68 + jb];
    float4 kv3 = *(const float4*)&Bm[(dc * 4 + 3) * 68 + jb];
    #pragma unroll
    for (int r = 0; r < 4; ++r) {
      float4 af = *(const float4*)&A[r * 68 + dc * 4];
      s[r][0] += af.x * kv0.x; s[r][1] += af.x * kv0.y; s[r][2] += af.x * kv0.z; s[r][3] += af.x * kv0.w;
      s[r][0] += af.y * kv1.x; s[r][1] += af.y * kv1.y; s[r][2] += af.y * kv1.z; s[r][3] += af.y * kv1.w;
      s[r][0] += af.z * kv2.x; s[r][1] += af.z * kv2.y; s[r][2] += af.z * kv2.z; s[r][3] += af.z * kv2.w;
      s[r][0] += af.w * kv3.x; s[r][1] += af.w * kv3.y; s[r][2] += af.w * kv3.z; s[r][3] += af.w * kv3.w;
    }
  }
}

// Stage a 128x64 tile (2048 float4) into LDS [128][68], 512 threads.
__device__ __forceinline__ void stage_q(float* __restrict__ dst,
                                        const float4* __restrict__ src, int tid) {
  int sr = tid >> 4, sc = (tid & 15) * 4;   // sr 0..31
  float4 a = src[tid];
  float4 b = src[tid + 512];
  float4 c = src[tid + 1024];
  float4 d = src[tid + 1536];
  *(float4*)&dst[sr * 68 + sc] = a;
  *(float4*)&dst[(32 + sr) * 68 + sc] = b;
  *(float4*)&dst[(64 + sr) * 68 + sc] = c;
  *(float4*)&dst[(96 + sr) * 68 + sc] = d;
}

// Stage a 64x64 tile (1024 float4) into LDS [64][68], 512 threads.
__device__ __forceinline__ void stage_l(float* __restrict__ dst,
                                        const float4* __restrict__ src, int tid) {
  int sr = tid >> 4, sc = (tid & 15) * 4;   // sr 0..31
  float4 a = src[tid];
  float4 b = src[tid + 512];
  *(float4*)&dst[sr * 68 + sc] = a;
  *(float4*)&dst[(32 + sr) * 68 + sc] = b;
}

__global__ void __launch_bounds__(512) k_final(const float* __restrict__ q,
                                               const float* __restrict__ klT,
                                               const float* __restrict__ T2,
                                               const float* __restrict__ Wsim1,
                                               const float* __restrict__ Wattn1,
                                               float* __restrict__ out) {
  // LDS: Q0|Q1 (128x68 each) + L0|L1 (64x68 each) + weights = 102.5 KB.
  __shared__ float SB[2 * 128 * 68 + 2 * 64 * 68];
  __shared__ float ws1[64], wa1[64];
  constexpr int PITCH = 68, QBUF = 128 * 68, LBUF = 64 * 68;
  float* Q0 = SB;
  float* L0 = SB + 2 * QBUF;
  int b = blockIdx.x >> 5, i0 = (blockIdx.x & 31) * 128;
  int tid = threadIdx.x;
  if (tid < 64) { ws1[tid] = Wsim1[tid]; wa1[tid] = Wattn1[tid]; }
  int jb = (tid & 15) * 4, r0 = (tid >> 4) * 4;   // r0 0..124

  float sim[8][4][4] = {};   // [k][row][col] = 128 VGPR

  const float4* qb = (const float4*)(q + ((size_t)(b * 8) * cN + i0) * 64);
  const float4* kb = (const float4*)(klT + (size_t)(b * 8) * 4096);
  const float4* tb = (const float4*)(T2 + (size_t)(b * 8) * 4096);

  // prologue: h=0 tiles into buffer 0
  stage_q(Q0, qb, tid);
  stage_l(L0, kb, tid);
  __syncthreads();

  // ---- phase 1: h = 0..6 (stage h+1 at top, compute h, barrier) ----
  for (int h = 0; h < 7; ++h) {
    int p = h & 1, pn = p ^ 1;
    stage_q(Q0 + pn * QBUF, qb + (size_t)(h + 1) * 65536, tid);
    stage_l(L0 + pn * LBUF, kb + (size_t)(h + 1) * 1024, tid);
    float s[4][4] = {};
    dot64_4x4(Q0 + p * QBUF + r0 * PITCH, L0 + p * LBUF, jb, s);
    #pragma unroll
    for (int kq = 0; kq < 8; ++kq) {
      float wv = ws1[h * 8 + kq];
      #pragma unroll
      for (int r = 0; r < 4; ++r)
        #pragma unroll
        for (int c = 0; c < 4; ++c) sim[kq][r][c] += wv * s[r][c];
    }
    __syncthreads();
  }

  // ---- h = 7 (p = 1): stage T2[0] -> L0, compute, softmax+mix, P0 -> Q0 ----
  {
    stage_l(L0, tb, tid);
    float s[4][4] = {};
    dot64_4x4(Q0 + 1 * QBUF + r0 * PITCH, L0 + 1 * LBUF, jb, s);
    #pragma unroll
    for (int kq = 0; kq < 8; ++kq) {
      float wv = ws1[56 + kq];
      #pragma unroll
      for (int r = 0; r < 4; ++r)
        #pragma unroll
        for (int c = 0; c < 4; ++c) sim[kq][r][c] += wv * s[r][c];
    }
    // softmax over j=64 (16 lanes x 4 cols) for each of the 4 rows
    #pragma unroll
    for (int kq = 0; kq < 8; ++kq) {
      #pragma unroll
      for (int r = 0; r < 4; ++r) {
        float mx = fmaxf(fmaxf(sim[kq][r][0], sim[kq][r][1]),
                         fmaxf(sim[kq][r][2], sim[kq][r][3]));
        mx = fmaxf(mx, __shfl_xor(mx, 1)); mx = fmaxf(mx, __shfl_xor(mx, 2));
        mx = fmaxf(mx, __shfl_xor(mx, 4)); mx = fmaxf(mx, __shfl_xor(mx, 8));
        float sm = 0.f;
        #pragma unroll
        for (int c = 0; c < 4; ++c) {
          sim[kq][r][c] = expf(sim[kq][r][c] - mx);
          sm += sim[kq][r][c];
        }
        sm += __shfl_xor(sm, 1); sm += __shfl_xor(sm, 2);
        sm += __shfl_xor(sm, 4); sm += __shfl_xor(sm, 8);
        float inv = 1.0f / sm;
        #pragma unroll
        for (int c = 0; c < 4; ++c) sim[kq][r][c] *= inv;
      }
    }
    // Wattn1 mix in registers
    #pragma unroll
    for (int r = 0; r < 4; ++r)
      #pragma unroll
      for (int c = 0; c < 4; ++c) {
        float t[8];
        #pragma unroll
        for (int k2 = 0; k2 < 8; ++k2) {
          float a = 0.f;
          #pragma unroll
          for (int kk = 0; kk < 8; ++kk) a += sim[kk][r][c] * wa1[kk * 8 + k2];
          t[k2] = a;
        }
        #pragma unroll
        for (int k2 = 0; k2 < 8; ++k2) sim[k2][r][c] = t[k2];
      }
    // P[0] -> Q0
    #pragma unroll
    for (int r = 0; r < 4; ++r)
      *(float4*)&Q0[(r0 + r) * PITCH + jb] =
          make_float4(sim[0][r][0], sim[0][r][1], sim[0][r][2], sim[0][r][3]);
    __syncthreads();
  }

  // ---- phase 2: out[k2] += P[k2] @ T2[k2]; immediate global RMW per k2 ----
  #pragma unroll
  for (int k2 = 0; k2 < 8; ++k2) {
    int p = k2 & 1, pn = p ^ 1;
    if (k2 < 7) {
      stage_l(L0 + pn * LBUF, tb + (size_t)(k2 + 1) * 1024, tid);
      #pragma unroll
      for (int r = 0; r < 4; ++r)
        *(float4*)&Q0[pn * QBUF + (r0 + r) * PITCH + jb] =
            make_float4(sim[k2 + 1][r][0], sim[k2 + 1][r][1],
                        sim[k2 + 1][r][2], sim[k2 + 1][r][3]);
    }
    float o[4][4] = {};
    dot64_4x4(Q0 + p * QBUF + r0 * PITCH, L0 + p * LBUF, jb, o);
    #pragma unroll
    for (int r = 0; r < 4; ++r) {
      float* op = out + ((size_t)(b * 8 + k2) * cN + i0 + r0 + r) * 64 + jb;
      float4 e = *(float4*)op;
      e.x += o[r][0]; e.y += o[r][1]; e.z += o[r][2]; e.w += o[r][3];
      *(float4*)op = e;
    }
    if (k2 < 7) __syncthreads();
  }
}

// ---------------------------------------------------------------------------
extern "C" void kernel_launch(void* const* d_in, const int* in_sizes, int n_in,
                              void* d_out, int out_size, void* d_ws, size_t ws_size,
                              hipStream_t stream) {
  const float* q = (const float*)d_in[0];
  const float* k = (const float*)d_in[1];
  const float* v = (const float*)d_in[2];
  const float* Wsim1 = (const float*)d_in[3];
  const float* Wsim2 = (const float*)d_in[4];
  const float* Wsim3 = (const float*)d_in[5];
  const float* Wattn1 = (const float*)d_in[6];
  const float* Wattn2 = (const float*)d_in[7];
  const float* Wattn3 = (const float*)d_in[8];
  const float* cw = (const float*)d_in[9];
  float* out = (float*)d_out;
  float* ws = (float*)d_ws;

  float* ql       = ws + 0;
  float* kl       = ws + 262144;
  float* attn2    = ws + 524288;
  float* attn2inv = ws + 786432;
  float* klT      = ws + 1048576;  // was attn2m (freed by mix-in-t2 fusion)
  float* T2       = ws + 1310720;
  unsigned int* scal = (unsigned int*)(ws + 1581056);
  float* T3p      = ws + 1581120;  // 4 * 64 * 4096 = 1,048,576 floats
  // d_out (exactly B*H*64*N floats) doubles as sim3m scratch; fully consumed
  // by k_t3 before k_conv overwrites d_out with the conv residual.
  float* sim3m = out;

  hipMemsetAsync(scal, 0, 8, stream);
  k_landmarks<<<dim3(4096), dim3(64), 0, stream>>>(q, k, ql, kl);
  // k_sim2 also emits klT (transposed kl) -- k_klT kernel deleted (R10)
  k_sim2<<<dim3(64), dim3(256), 0, stream>>>(ql, kl, Wsim2, attn2, scal, klT);
  k_pinv<<<dim3(64), dim3(256), 0, stream>>>(attn2, attn2inv, scal);
  k_sim3<<<dim3(1024), dim3(512), 0, stream>>>(ql, k, Wsim3, sim3m);
  // fused row-stats + softmax + Wattn3 mix, in place on sim3m
  k_smxt3<<<dim3(512), dim3(512), 0, stream>>>(sim3m, Wattn3);
  k_t3<<<dim3(256), dim3(256), 0, stream>>>(sim3m, v, T3p);
  // k_t2 computes attn2m on the fly from attn2inv+Wattn2 -- k_mix deleted (R10)
  k_t2<<<dim3(64), dim3(256), 0, stream>>>(attn2inv, Wattn2, T3p, T2);
  k_conv<<<dim3(1024), dim3(256), 0, stream>>>(v, cw, out);
  k_final<<<dim3(256), dim3(512), 0, stream>>>(q, klT, T2, Wsim1, Wattn1, out);
}